// Round 7
// baseline (24475.629 us; speedup 1.0000x reference)
//
#include <hip/hip_runtime.h>

// ---------------------------------------------------------------------------
// MotionGenerator RNN for MI355X (gfx950).
//  - encoder: im2col + bf16 MFMA GEMM (weights are [out,in] == [N,K] B^T layout)
//  - decoder: weight-stationary persistent DATAFLOW kernel, 212 blocks.
//    No global barrier: per-producer-group ready counters (ringed per step);
//    each consumer block polls ONE counter with ONE thread. Activations ride
//    never-reused rings (emb/h0/h1/stats full 540-slot; Gx/Xal/Gal mod-8,
//    reuse gated by counters). Producers store uncached (sc0 sc1,
//    write-through); consumers read fresh addresses CACHED (L2 multicast).
// ---------------------------------------------------------------------------

typedef unsigned short u16;
typedef __attribute__((ext_vector_type(8))) short short8;
typedef __attribute__((ext_vector_type(4))) float f32x4;

#define GELU_FLG 1
#define BF16_FLG 2
#define NBLK 212
#define DEC_STEPS 540

__device__ __forceinline__ u16 f2b(float f){
  union { float f; unsigned u; } c; c.f = f;
  return (u16)((c.u + 0x7fffu + ((c.u >> 16) & 1u)) >> 16);   // RNE
}
__device__ __forceinline__ short8 ld8(const u16* p){
  return *reinterpret_cast<const short8*>(p);
}
// coherent (agent-scope, cache-bypass) accessors for cross-block data
__device__ __forceinline__ float ldfc(const float* p){
  return __hip_atomic_load(p, __ATOMIC_RELAXED, __HIP_MEMORY_SCOPE_AGENT);
}
__device__ __forceinline__ void stfc(float* p, float v){
  __hip_atomic_store(p, v, __ATOMIC_RELAXED, __HIP_MEMORY_SCOPE_AGENT);
}
__device__ __forceinline__ void stu32c(u16* p, unsigned v){
  __hip_atomic_store((unsigned*)p, v, __ATOMIC_RELAXED, __HIP_MEMORY_SCOPE_AGENT);
}
__device__ __forceinline__ void st16c(u16* p, unsigned v){
  asm volatile("global_store_short %0, %1, off sc0 sc1" :: "v"(p), "v"(v) : "memory");
}
__device__ __forceinline__ f32x4 mfma16(short8 a, short8 b, f32x4 c){
  return __builtin_amdgcn_mfma_f32_16x16x32_bf16(a, b, c, 0, 0, 0);
}
__device__ __forceinline__ float gelu_f(float x){
  return 0.5f * x * (1.f + erff(x * 0.70710678118654752f));   // exact gelu
}
__device__ __forceinline__ float sigmoid_f(float x){
  return 1.f / (1.f + __expf(-x));
}
__device__ __forceinline__ float tanh_f(float x){
  float e = __expf(-2.f * x);
  return (1.f - e) / (1.f + e);
}

// ---------------- elementwise / gather kernels ----------------

__global__ void f2b_k(const float* __restrict__ s, u16* __restrict__ d, int n){
  int i = blockIdx.x * 256 + threadIdx.x;
  if (i < n) d[i] = f2b(s[i]);
}

__global__ void gather_xc_k(const float* __restrict__ mo, const float* __restrict__ lxm,
                            u16* __restrict__ xc, u16* __restrict__ pre_mo){
  int i = blockIdx.x * 256 + threadIdx.x;
  if (i >= 32 * 384) return;
  int n = i / 384, c = i - n * 384;
  float v = (c < 256) ? mo[(size_t)(n * 256 + c) * 600 + 29]
                      : lxm[(size_t)(n * 128 + (c - 256)) * 20];
  u16 h = f2b(v);
  xc[i] = h;
  if (c < 256) pre_mo[n * 256 + c] = h;
}

__global__ void lxm_g_k(const float* __restrict__ lxm, u16* __restrict__ o){
  int i = blockIdx.x * 256 + threadIdx.x;
  if (i >= 18 * 32 * 128) return;
  int c = i & 127, rest = i >> 7;
  int n = rest & 31, b = rest >> 5;
  o[i] = f2b(lxm[(size_t)(n * 128 + c) * 20 + 1 + b]);
}

__global__ void split_h_k(const float* __restrict__ hraw, u16* __restrict__ h0, u16* __restrict__ h1,
                          float* __restrict__ h0f, float* __restrict__ h1f){
  int i = blockIdx.x * 256 + threadIdx.x;
  if (i >= 32 * 1024) return;
  int n = i >> 10, c = i & 1023;
  float a = hraw[(size_t)n * 2048 + c];
  float b = hraw[(size_t)n * 2048 + 1024 + c];
  h0[i] = f2b(a); h1[i] = f2b(b);
  h0f[i] = a;     h1f[i] = b;
}

__global__ void build_xc0_k(const u16* __restrict__ pre_mo, const u16* __restrict__ aud_seq,
                            const u16* __restrict__ lxm_b, u16* __restrict__ xc0){
  int i = blockIdx.x * 256 + threadIdx.x;
  if (i >= 32 * 640) return;
  int n = i / 640, c = i - n * 640;
  u16 v;
  if (c < 256) v = pre_mo[n * 256 + c];
  else if (c < 512) v = aud_seq[n * 256 + (c - 256)];
  else v = lxm_b[n * 128 + (c - 512)];
  xc0[i] = v;
}

__global__ void t_wpT_k(const float* __restrict__ wp, u16* __restrict__ wpT){
  int i = blockIdx.x * 256 + threadIdx.x;
  if (i >= 1024 * 256) return;
  int h = i >> 8, j = i & 255;
  wpT[i] = f2b(wp[(size_t)j * 1024 + h]);
}

// fold LN gain/bias into a [R x 1024] matrix that acts on LN(h1)
__global__ void foldW_k(const float* __restrict__ src, const float* __restrict__ g,
                        const float* __restrict__ b, const float* __restrict__ addb,
                        u16* __restrict__ Wg, float* __restrict__ S, float* __restrict__ B, int R){
  int row = blockIdx.x * 4 + (threadIdx.x >> 6);
  if (row >= R) return;
  int lane = threadIdx.x & 63;
  const float* sr = src + (size_t)row * 1024;
  float s = 0.f, bb = 0.f;
  #pragma unroll
  for (int k = 0; k < 16; ++k){
    int c = lane + k * 64;
    float w = sr[c], gw = w * g[c];
    Wg[(size_t)row * 1024 + c] = f2b(gw);
    s += gw; bb += w * b[c];
  }
  #pragma unroll
  for (int m = 1; m < 64; m <<= 1){ s += __shfl_xor(s, m); bb += __shfl_xor(bb, m); }
  if (lane == 0){ S[row] = s; B[row] = bb + (addb ? addb[row] : 0.f); }
}

// v[row] = base[row] + sum_{j<256} W[row*ldw + off + j] * pb[j]
__global__ void vfold_k(const float* __restrict__ W, int ldw, int off, const float* __restrict__ pb,
                        const float* __restrict__ base, float* __restrict__ v, int R){
  int row = blockIdx.x * 4 + (threadIdx.x >> 6);
  if (row >= R) return;
  int lane = threadIdx.x & 63;
  const float* wr = W + (size_t)row * ldw + off;
  float s = 0.f;
  #pragma unroll
  for (int k = 0; k < 4; ++k){ int j = lane + k * 64; s += wr[j] * pb[j]; }
  #pragma unroll
  for (int m = 1; m < 64; m <<= 1) s += __shfl_xor(s, m);
  if (lane == 0) v[row] = s + (base ? base[row] : 0.f);
}

// ---------------- im2col kernels ----------------

__global__ void im2col0_k(const float* __restrict__ aud, u16* __restrict__ A, int row0, long long tot){
  long long i = (long long)blockIdx.x * 256 + threadIdx.x;
  if (i >= tot) return;
  int k = (int)(i % 896);
  int row = row0 + (int)(i / 896);
  int ci = k / 7, kk = k - ci * 7;
  int p = row % 84, bn = row / 84;
  int b = bn >> 5, n = bn & 31;
  A[i] = f2b(aud[(size_t)(n * 128 + ci) * 600 + b * 30 + p + kk]);
}

__global__ void im2col1_k(const u16* __restrict__ O0, u16* __restrict__ A, int row0, long long tot){
  long long i = (long long)blockIdx.x * 256 + threadIdx.x;
  if (i >= tot) return;
  int k = (int)(i % 1280);
  int row = row0 + (int)(i / 1280);
  int ci = k / 5, kk = k - ci * 5;
  int p = row % 80, bn = row / 80;
  A[i] = O0[(size_t)(bn * 84 + p + kk) * 256 + ci];
}

__global__ void im2col2_k(const u16* __restrict__ O1, u16* __restrict__ A, int row0, long long tot){
  long long i = (long long)blockIdx.x * 256 + threadIdx.x;
  if (i >= tot) return;
  int k = (int)(i & 1023);
  int row = row0 + (int)(i >> 10);
  int ci = k >> 2, kk = k & 3;
  int p = row % 40, bn = row / 40;
  int pos = 2 * p - 1 + kk;                      // stride 2, pad 1
  A[i] = (pos >= 0 && pos < 80) ? O1[(size_t)(bn * 80 + pos) * 256 + ci] : (u16)0;
}

// ---------------- GEMM: C[M,N] = A[M,K] @ W[N,K]^T  (bf16 MFMA) ----------------

__global__ void gemm_bt(const u16* __restrict__ A, int lda,
                        const u16* __restrict__ W, int ldw, const float* __restrict__ bias,
                        void* __restrict__ outp, int M, int N, int K, int flags){
  const int lane = threadIdx.x & 63, widx = threadIdx.x >> 6;
  const int m0 = blockIdx.x * 64 + widx * 16;
  if (m0 >= M) return;
  const int n0 = blockIdx.y * 64;
  const int r = lane & 15, g4 = lane >> 4;
  const u16* arow = A + (size_t)(m0 + r) * lda + g4 * 8;
  const u16* wrow = W + (size_t)(n0 + r) * ldw + g4 * 8;
  f32x4 acc[4];
  const f32x4 FZ = {0.f, 0.f, 0.f, 0.f};
  acc[0] = FZ; acc[1] = FZ; acc[2] = FZ; acc[3] = FZ;
  for (int k = 0; k < K; k += 32){
    short8 a = ld8(arow + k);
    #pragma unroll
    for (int j = 0; j < 4; ++j)
      acc[j] = mfma16(a, ld8(wrow + (size_t)j * 16 * ldw + k), acc[j]);
  }
  #pragma unroll
  for (int j = 0; j < 4; ++j){
    int col = n0 + j * 16 + r;
    float bv = bias ? bias[col] : 0.f;
    #pragma unroll
    for (int q = 0; q < 4; ++q){
      int row = m0 + g4 * 4 + q;
      float v = acc[j][q] + bv;
      if (flags & GELU_FLG) v = gelu_f(v);
      if (flags & BF16_FLG) ((u16*)outp)[(size_t)row * N + col] = f2b(v);
      else                  ((float*)outp)[(size_t)row * N + col] = v;
    }
  }
}

// ---------------- encoder LayerNorm -> aud_seq (bf16) ----------------

__global__ void enc_ln_k(const float* __restrict__ O3, const float* __restrict__ g,
                         const float* __restrict__ bb, u16* __restrict__ aud_seq){
  int rid = blockIdx.x * 4 + (threadIdx.x >> 6);
  int lane = threadIdx.x & 63;
  int b = rid / 960, rem = rid - b * 960;
  int p2 = rem >> 5, n = rem & 31;
  int orow = (b * 32 + n) * 40 + p2;
  const float4 v = *reinterpret_cast<const float4*>(O3 + (size_t)orow * 256 + lane * 4);
  float s  = v.x + v.y + v.z + v.w;
  float s2 = v.x * v.x + v.y * v.y + v.z * v.z + v.w * v.w;
  #pragma unroll
  for (int m = 1; m < 64; m <<= 1){ s += __shfl_xor(s, m); s2 += __shfl_xor(s2, m); }
  float mu = s * (1.f / 256.f);
  float var = s2 * (1.f / 256.f) - mu * mu;
  float rs = rsqrtf(var + 1e-5f);
  int c = lane * 4;
  u16* dst = aud_seq + (size_t)rid * 256 + c;
  dst[0] = f2b((v.x - mu) * rs * g[c + 0] + bb[c + 0]);
  dst[1] = f2b((v.y - mu) * rs * g[c + 1] + bb[c + 1]);
  dst[2] = f2b((v.z - mu) * rs * g[c + 2] + bb[c + 2]);
  dst[3] = f2b((v.w - mu) * rs * g[c + 3] + bb[c + 3]);
}

// ---------------- persistent weight-stationary dataflow decoder ----------------

struct DecArgs {
  const u16 *aud_seq, *lxm_b;
  const u16 *wih0, *whh0, *wih1, *whh1, *wd;       // bf16 blobs
  const u16 *wpg, *Wdpg, *Wgpg;                    // LN-folded PE weights
  const float *Sp, *Bp, *S1, *B1, *S2, *B2, *vX, *vG;
  const float *bih0, *bhh0, *bih1, *bhh1;
  const u16 *h0init, *h1init;
  u16 *embR, *h0R, *h1R;                 // rings: slot t = 32x1024 bf16 (64 KB)
  float *statsR;                         // ring:  slot t = [64 blk][64] f32
  float *GxR, *XalR, *GalR;              // mod-8 rings (counter-gated reuse)
  float *h0f, *h1f, *out;
  int *cnt;                              // [4 groups][544 steps][16 ints]
};

// dataflow signal/wait: one atomicAdd per producer block, one poller thread
// per consumer block.
__device__ __forceinline__ void sigcnt(int* c){
  asm volatile("s_waitcnt vmcnt(0)" ::: "memory");   // drain this wave's stores
  __syncthreads();                                   // all waves drained
  if (threadIdx.x == 0) atomicAdd(c, 1);
}
__device__ __forceinline__ void waitge(const int* c, int tgt){
  if (threadIdx.x == 0){
    while (__hip_atomic_load(c, __ATOMIC_RELAXED, __HIP_MEMORY_SCOPE_AGENT) < tgt)
      __builtin_amdgcn_s_sleep(1);
  }
  __syncthreads();
}

__global__ __launch_bounds__(256, 1) void decode_k(DecArgs A){
  const int tid = threadIdx.x;
  const int lane = tid & 63, q = tid >> 6;
  const int r = lane & 15, g4 = lane >> 4;
  const int blk = blockIdx.x;
  __shared__ float lds[4][4][32][17];                // pad 17: no bank conflicts
  const f32x4 FZ = {0.f, 0.f, 0.f, 0.f};
  int* const cH0 = A.cnt;                            // [544][16]
  int* const cH1 = A.cnt + 544 * 16;
  int* const cPE = A.cnt + 1088 * 16;
  int* const cAL = A.cnt + 1632 * 16;

  if (blk < 64){
    // ---------------- L0: h0 producer (wih0_e + whh0 resident) ----------------
    const int c0 = blk * 16;
    const int kq = q * 256;
    short8 we[24], wh[24];
    #pragma unroll
    for (int g = 0; g < 3; ++g)
      #pragma unroll
      for (int ch = 0; ch < 8; ++ch){
        we[g * 8 + ch] = ld8(A.wih0 + (size_t)(g * 1024 + c0 + r) * 1664 + kq + ch * 32 + g4 * 8);
        wh[g * 8 + ch] = ld8(A.whh0 + (size_t)(g * 1024 + c0 + r) * 1024 + kq + ch * 32 + g4 * 8);
      }
    const int n_c = tid >> 3;
    const int cc0 = (tid & 7) * 2;
    const int colA = c0 + cc0, colB = colA + 1;
    const float bi_r[2] = {A.bih0[colA], A.bih0[colB]};
    const float bi_z[2] = {A.bih0[1024 + colA], A.bih0[1024 + colB]};
    const float bi_n[2] = {A.bih0[2048 + colA], A.bih0[2048 + colB]};
    const float bh_r[2] = {A.bhh0[colA], A.bhh0[colB]};
    const float bh_z[2] = {A.bhh0[1024 + colA], A.bhh0[1024 + colB]};
    const float bh_n[2] = {A.bhh0[2048 + colA], A.bhh0[2048 + colB]};
    f32x4 ar[2], az[2], ani[2], anh[2];
    // pre-loop: gh0 on initial h0 (cross-kernel cached read; dispatch acquire)
    ar[0] = FZ; ar[1] = FZ; az[0] = FZ; az[1] = FZ; ani[0] = FZ; ani[1] = FZ; anh[0] = FZ; anh[1] = FZ;
    #pragma unroll
    for (int ch = 0; ch < 8; ++ch){
      short8 a0 = ld8(A.h0init + r * 1024 + kq + ch * 32 + g4 * 8);
      short8 a1 = ld8(A.h0init + (16 + r) * 1024 + kq + ch * 32 + g4 * 8);
      ar[0] = mfma16(a0, wh[ch], ar[0]);        ar[1] = mfma16(a1, wh[ch], ar[1]);
      az[0] = mfma16(a0, wh[8 + ch], az[0]);    az[1] = mfma16(a1, wh[8 + ch], az[1]);
      anh[0] = mfma16(a0, wh[16 + ch], anh[0]); anh[1] = mfma16(a1, wh[16 + ch], anh[1]);
    }
    #pragma unroll 1
    for (int t = 0; t < DEC_STEPS; ++t){
      if (t > 0) waitge(cPE + (t - 1) * 16, 68);      // emb[t], Gx[t] ready
      const u16*  embT = A.embR + (size_t)t * 32768;
      u16*        h0T  = A.h0R  + (size_t)t * 32768;
      const float* GxT = A.GxR + (size_t)(t & 7) * 98304;
      float pgr[2], pgz[2], pgn[2], phf[2];
      #pragma unroll
      for (int e = 0; e < 2; ++e){
        int col = c0 + cc0 + e;
        pgr[e] = ldfc(GxT + n_c * 3072 + col);
        pgz[e] = ldfc(GxT + n_c * 3072 + 1024 + col);
        pgn[e] = ldfc(GxT + n_c * 3072 + 2048 + col);
        phf[e] = A.h0f[n_c * 1024 + col];
      }
      #pragma unroll
      for (int ch = 0; ch < 8; ++ch){
        short8 a0 = ld8(embT + r * 1024 + kq + ch * 32 + g4 * 8);
        short8 a1 = ld8(embT + (16 + r) * 1024 + kq + ch * 32 + g4 * 8);
        ar[0] = mfma16(a0, we[ch], ar[0]);        ar[1] = mfma16(a1, we[ch], ar[1]);
        az[0] = mfma16(a0, we[8 + ch], az[0]);    az[1] = mfma16(a1, we[8 + ch], az[1]);
        ani[0] = mfma16(a0, we[16 + ch], ani[0]); ani[1] = mfma16(a1, we[16 + ch], ani[1]);
      }
      #pragma unroll
      for (int m = 0; m < 2; ++m)
        #pragma unroll
        for (int j = 0; j < 4; ++j){
          int row = m * 16 + g4 * 4 + j;
          lds[q][0][row][r] = ar[m][j];
          lds[q][1][row][r] = az[m][j];
          lds[q][2][row][r] = ani[m][j];
          lds[q][3][row][r] = anh[m][j];
        }
      __syncthreads();
      float hv2[2];
      #pragma unroll
      for (int e = 0; e < 2; ++e){
        int cc = cc0 + e, col = c0 + cc;
        float sr = bi_r[e] + bh_r[e] + pgr[e];
        float sz = bi_z[e] + bh_z[e] + pgz[e];
        float si = bi_n[e] + pgn[e];
        float sh = bh_n[e];
        #pragma unroll
        for (int qq = 0; qq < 4; ++qq){
          sr += lds[qq][0][n_c][cc]; sz += lds[qq][1][n_c][cc];
          si += lds[qq][2][n_c][cc]; sh += lds[qq][3][n_c][cc];
        }
        float rg = sigmoid_f(sr), zg = sigmoid_f(sz);
        float ng = tanh_f(si + rg * sh);
        float hv = (1.f - zg) * ng + zg * phf[e];
        A.h0f[n_c * 1024 + col] = hv;            // private, cached
        hv2[e] = hv;
      }
      stu32c(h0T + n_c * 1024 + colA,
             (unsigned)f2b(hv2[0]) | ((unsigned)f2b(hv2[1]) << 16));
      __syncthreads();                           // lds reuse guard
      sigcnt(cH0 + t * 16);
      waitge(cH0 + t * 16, 64);                  // full h0[t] for gh0-next
      ar[0] = FZ; ar[1] = FZ; az[0] = FZ; az[1] = FZ; ani[0] = FZ; ani[1] = FZ; anh[0] = FZ; anh[1] = FZ;
      #pragma unroll
      for (int ch = 0; ch < 8; ++ch){
        short8 a0 = ld8(h0T + r * 1024 + kq + ch * 32 + g4 * 8);
        short8 a1 = ld8(h0T + (16 + r) * 1024 + kq + ch * 32 + g4 * 8);
        ar[0] = mfma16(a0, wh[ch], ar[0]);        ar[1] = mfma16(a1, wh[ch], ar[1]);
        az[0] = mfma16(a0, wh[8 + ch], az[0]);    az[1] = mfma16(a1, wh[8 + ch], az[1]);
        anh[0] = mfma16(a0, wh[16 + ch], anh[0]); anh[1] = mfma16(a1, wh[16 + ch], anh[1]);
      }
    }
  } else if (blk < 128){
    // ---------------- L1: h1 producer (wih1 + whh1 resident) ----------------
    const int c0 = (blk - 64) * 16;
    const int kq = q * 256;
    short8 wi[24], wh[24];
    #pragma unroll
    for (int g = 0; g < 3; ++g)
      #pragma unroll
      for (int ch = 0; ch < 8; ++ch){
        wi[g * 8 + ch] = ld8(A.wih1 + (size_t)(g * 1024 + c0 + r) * 1024 + kq + ch * 32 + g4 * 8);
        wh[g * 8 + ch] = ld8(A.whh1 + (size_t)(g * 1024 + c0 + r) * 1024 + kq + ch * 32 + g4 * 8);
      }
    const int n_c = tid >> 3;
    const int cc0 = (tid & 7) * 2;
    const int colA = c0 + cc0, colB = colA + 1;
    const float bi_r[2] = {A.bih1[colA], A.bih1[colB]};
    const float bi_z[2] = {A.bih1[1024 + colA], A.bih1[1024 + colB]};
    const float bi_n[2] = {A.bih1[2048 + colA], A.bih1[2048 + colB]};
    const float bh_r[2] = {A.bhh1[colA], A.bhh1[colB]};
    const float bh_z[2] = {A.bhh1[1024 + colA], A.bhh1[1024 + colB]};
    const float bh_n[2] = {A.bhh1[2048 + colA], A.bhh1[2048 + colB]};
    f32x4 ar[2], az[2], ani[2], anh[2];
    // pre-loop: gh1 on initial h1
    ar[0] = FZ; ar[1] = FZ; az[0] = FZ; az[1] = FZ; ani[0] = FZ; ani[1] = FZ; anh[0] = FZ; anh[1] = FZ;
    #pragma unroll
    for (int ch = 0; ch < 8; ++ch){
      short8 a0 = ld8(A.h1init + r * 1024 + kq + ch * 32 + g4 * 8);
      short8 a1 = ld8(A.h1init + (16 + r) * 1024 + kq + ch * 32 + g4 * 8);
      ar[0] = mfma16(a0, wh[ch], ar[0]);        ar[1] = mfma16(a1, wh[ch], ar[1]);
      az[0] = mfma16(a0, wh[8 + ch], az[0]);    az[1] = mfma16(a1, wh[8 + ch], az[1]);
      anh[0] = mfma16(a0, wh[16 + ch], anh[0]); anh[1] = mfma16(a1, wh[16 + ch], anh[1]);
    }
    #pragma unroll 1
    for (int t = 0; t < DEC_STEPS; ++t){
      waitge(cH0 + t * 16, 64);                  // h0[t] ready
      const u16* h0T = A.h0R + (size_t)t * 32768;
      u16*       h1T = A.h1R + (size_t)t * 32768;
      float phf[2];
      phf[0] = A.h1f[n_c * 1024 + colA];
      phf[1] = A.h1f[n_c * 1024 + colB];
      #pragma unroll
      for (int ch = 0; ch < 8; ++ch){
        short8 a0 = ld8(h0T + r * 1024 + kq + ch * 32 + g4 * 8);
        short8 a1 = ld8(h0T + (16 + r) * 1024 + kq + ch * 32 + g4 * 8);
        ar[0] = mfma16(a0, wi[ch], ar[0]);        ar[1] = mfma16(a1, wi[ch], ar[1]);
        az[0] = mfma16(a0, wi[8 + ch], az[0]);    az[1] = mfma16(a1, wi[8 + ch], az[1]);
        ani[0] = mfma16(a0, wi[16 + ch], ani[0]); ani[1] = mfma16(a1, wi[16 + ch], ani[1]);
      }
      #pragma unroll
      for (int m = 0; m < 2; ++m)
        #pragma unroll
        for (int j = 0; j < 4; ++j){
          int row = m * 16 + g4 * 4 + j;
          lds[q][0][row][r] = ar[m][j];
          lds[q][1][row][r] = az[m][j];
          lds[q][2][row][r] = ani[m][j];
          lds[q][3][row][r] = anh[m][j];
        }
      __syncthreads();
      float hv2[2];
      #pragma unroll
      for (int e = 0; e < 2; ++e){
        int cc = cc0 + e, col = c0 + cc;
        float sr = bi_r[e] + bh_r[e];
        float sz = bi_z[e] + bh_z[e];
        float si = bi_n[e];
        float sh = bh_n[e];
        #pragma unroll
        for (int qq = 0; qq < 4; ++qq){
          sr += lds[qq][0][n_c][cc]; sz += lds[qq][1][n_c][cc];
          si += lds[qq][2][n_c][cc]; sh += lds[qq][3][n_c][cc];
        }
        float rg = sigmoid_f(sr), zg = sigmoid_f(sz);
        float ng = tanh_f(si + rg * sh);
        float hv = (1.f - zg) * ng + zg * phf[e];
        A.h1f[n_c * 1024 + col] = hv;            // private, cached
        hv2[e] = hv;
      }
      stu32c(h1T + n_c * 1024 + colA,
             (unsigned)f2b(hv2[0]) | ((unsigned)f2b(hv2[1]) << 16));
      float sv = hv2[0] + hv2[1], sq = hv2[0] * hv2[0] + hv2[1] * hv2[1];
      sv += __shfl_xor(sv, 1); sq += __shfl_xor(sq, 1);
      sv += __shfl_xor(sv, 2); sq += __shfl_xor(sq, 2);
      sv += __shfl_xor(sv, 4); sq += __shfl_xor(sq, 4);
      if ((tid & 7) == 0){
        stfc(A.statsR + (size_t)t * 4096 + (blk - 64) * 64 + n_c, sv);
        stfc(A.statsR + (size_t)t * 4096 + (blk - 64) * 64 + 32 + n_c, sq);
      }
      __syncthreads();                           // lds reuse guard
      sigcnt(cH1 + t * 16);
      waitge(cH1 + t * 16, 64);                  // full h1[t] for gh1-next
      ar[0] = FZ; ar[1] = FZ; az[0] = FZ; az[1] = FZ; ani[0] = FZ; ani[1] = FZ; anh[0] = FZ; anh[1] = FZ;
      #pragma unroll
      for (int ch = 0; ch < 8; ++ch){
        short8 a0 = ld8(h1T + r * 1024 + kq + ch * 32 + g4 * 8);
        short8 a1 = ld8(h1T + (16 + r) * 1024 + kq + ch * 32 + g4 * 8);
        ar[0] = mfma16(a0, wh[ch], ar[0]);        ar[1] = mfma16(a1, wh[ch], ar[1]);
        az[0] = mfma16(a0, wh[8 + ch], az[0]);    az[1] = mfma16(a1, wh[8 + ch], az[1]);
        anh[0] = mfma16(a0, wh[16 + ch], anh[0]); anh[1] = mfma16(a1, wh[16 + ch], anh[1]);
      }
    }
  } else if (blk < 196){
    // ---------------- PE: pred / emb_{t+1} / Gx_{t+1} on h1 (LN folded) ----------------
    const int tile = (blk - 128) * 4 + q;     // 0..271
    int jt, c0;
    const u16* wsrc; const float *Sv, *Bv;
    if (tile < 16)      { jt = 0; c0 = tile * 16;        wsrc = A.wpg;  Sv = A.Sp; Bv = A.Bp; }
    else if (tile < 80) { jt = 1; c0 = (tile - 16) * 16; wsrc = A.Wdpg; Sv = A.S1; Bv = A.B1; }
    else                { jt = 2; c0 = (tile - 80) * 16; wsrc = A.Wgpg; Sv = A.S2; Bv = A.B2; }
    short8 w[32];
    #pragma unroll
    for (int ch = 0; ch < 32; ++ch)
      w[ch] = ld8(wsrc + (size_t)(c0 + r) * 1024 + ch * 32 + g4 * 8);
    const float Sc = Sv[c0 + r], Bc = Bv[c0 + r];
    const int col = c0 + r;
    #pragma unroll 1
    for (int t = 0; t < DEC_STEPS; ++t){
      waitge(cH1 + t * 16, 64);                  // h1[t] + stats[t] ready
      waitge(cAL + (t + 1) * 16, 16);            // Xal/Gal[t+1] ready
      const u16*   h1T = A.h1R + (size_t)t * 32768;
      const float* stT = A.statsR + (size_t)t * 4096;
      const int sl = (t + 1) & 7;
      float sacc = 0.f;
      #pragma unroll
      for (int b2 = 0; b2 < 64; ++b2) sacc += stT[b2 * 64 + lane];
      float muA[2][4], rsA[2][4];
      #pragma unroll
      for (int m = 0; m < 2; ++m)
        #pragma unroll
        for (int j = 0; j < 4; ++j){
          int n = m * 16 + g4 * 4 + j;
          float sv = __shfl(sacc, n), sq = __shfl(sacc, 32 + n);
          float mu = sv * (1.f / 1024.f);
          muA[m][j] = mu;
          rsA[m][j] = rsqrtf(sq * (1.f / 1024.f) - mu * mu + 1e-5f);
        }
      f32x4 a0 = FZ, a1 = FZ;
      #pragma unroll
      for (int ch = 0; ch < 32; ++ch){
        short8 x0 = ld8(h1T + r * 1024 + ch * 32 + g4 * 8);
        short8 x1 = ld8(h1T + (16 + r) * 1024 + ch * 32 + g4 * 8);
        a0 = mfma16(x0, w[ch], a0);
        a1 = mfma16(x1, w[ch], a1);
      }
      u16*   embN = A.embR + (size_t)(t + 1) * 32768;
      float* GxN  = A.GxR + (size_t)sl * 98304;
      const float* XalT = A.XalR + (size_t)sl * 32768;
      const float* GalT = A.GalR + (size_t)sl * 98304;
      #pragma unroll
      for (int m = 0; m < 2; ++m)
        #pragma unroll
        for (int j = 0; j < 4; ++j){
          int n = m * 16 + g4 * 4 + j;
          float acc = (m ? a1[j] : a0[j]);
          float v = rsA[m][j] * (acc - muA[m][j] * Sc) + Bc;
          if (jt == 0){
            A.out[(size_t)n * (256 * 540) + (size_t)col * 540 + t] = v;   // cached; kernel-end flush
          } else if (jt == 1){
            float pre = v + ldfc(XalT + n * 1024 + col);
            st16c(embN + n * 1024 + col, (unsigned)f2b(gelu_f(pre)));
          } else {
            stfc(GxN + n * 3072 + col, v + ldfc(GalT + n * 3072 + col));
          }
        }
      sigcnt(cPE + t * 16);
    }
  } else {
    // ---------------- AL: audio/lxm partials for step t+1 ----------------
    const int wg = (blk - 196) * 4 + q;       // 0..63
    const int at0 = wg * 4;
    short8 w[48];
    float vb[4];
    #pragma unroll
    for (int j = 0; j < 4; ++j){
      int at = at0 + j;
      if (at < 64){
        #pragma unroll
        for (int ch = 0; ch < 12; ++ch)
          w[j * 12 + ch] = ld8(A.wd + (size_t)(at * 16 + r) * 640 + 256 + ch * 32 + g4 * 8);
        vb[j] = A.vX[at * 16 + r];
      } else {
        #pragma unroll
        for (int ch = 0; ch < 12; ++ch)
          w[j * 12 + ch] = ld8(A.wih0 + (size_t)((at - 64) * 16 + r) * 1664 + 1280 + ch * 32 + g4 * 8);
        vb[j] = A.vG[(at - 64) * 16 + r];
      }
    }
    #pragma unroll 1
    for (int t = 0; t < DEC_STEPS; ++t){
      if (t >= 8) waitge(cPE + (t - 8) * 16, 68);    // slot (t+1)&7 free
      const int tn = t + 1;
      const int tread = (tn > 539) ? 539 : tn;
      const int bn = tread / 30;
      const int sl = tn & 7;
      float* XalW = A.XalR + (size_t)sl * 32768;
      float* GalW = A.GalR + (size_t)sl * 98304;
      short8 af0[12], af1[12];
      #pragma unroll
      for (int ch = 0; ch < 12; ++ch){
        int kk = ch * 32 + g4 * 8;
        if (ch < 8){
          af0[ch] = ld8(A.aud_seq + ((size_t)tread * 32 + r) * 256 + kk);
          af1[ch] = ld8(A.aud_seq + ((size_t)tread * 32 + 16 + r) * 256 + kk);
        } else {
          af0[ch] = ld8(A.lxm_b + ((size_t)bn * 32 + r) * 128 + kk - 256);
          af1[ch] = ld8(A.lxm_b + ((size_t)bn * 32 + 16 + r) * 128 + kk - 256);
        }
      }
      #pragma unroll
      for (int j = 0; j < 4; ++j){
        f32x4 c0a = FZ, c1a = FZ;
        #pragma unroll
        for (int ch = 0; ch < 12; ++ch){
          c0a = mfma16(af0[ch], w[j * 12 + ch], c0a);
          c1a = mfma16(af1[ch], w[j * 12 + ch], c1a);
        }
        int at = at0 + j;
        #pragma unroll
        for (int m = 0; m < 2; ++m)
          #pragma unroll
          for (int jj = 0; jj < 4; ++jj){
            int n = m * 16 + g4 * 4 + jj;
            float v = (m ? c1a[jj] : c0a[jj]) + vb[j];
            if (at < 64) stfc(XalW + n * 1024 + at * 16 + r, v);
            else         stfc(GalW + n * 3072 + (at - 64) * 16 + r, v);
          }
      }
      sigcnt(cAL + tn * 16);
    }
  }
}

// ---------------------------------------------------------------------------

extern "C" void kernel_launch(void* const* d_in, const int* in_sizes, int n_in,
                              void* d_out, int out_size, void* d_ws, size_t ws_size,
                              hipStream_t stream) {
  enum { I_AUD=0, I_MO=1, I_LXM=2, I_AEW0=3, I_AEB0=4, I_AEW1=5, I_AEB1=6, I_AEW2=7, I_AEB2=8,
         I_AEW3=9, I_AEB3=10, I_AELNG=11, I_AELNB=12, I_CIW0=13, I_CIB0=14, I_CIW1=15, I_CIB1=16,
         I_CIW2=17, I_CIB2=18, I_DECW=19, I_DECB=20, I_WIH0=21, I_WHH0=22, I_BIH0=23, I_BHH0=24,
         I_WIH1=25, I_WHH1=26, I_BIH1=27, I_BHH1=28, I_LNG=29, I_LNB=30, I_PREDW=31, I_PREDB=32 };

  char* base = (char*)d_ws;
  size_t off = 0;
  auto alloc = [&](size_t bytes)->void*{
    void* p = base + off;
    off += (bytes + 255) & ~(size_t)255;
    return p;
  };

  // bf16 weight blobs
  u16* wd_b   = (u16*)alloc((size_t)1024*640*2);
  u16* wih0_b = (u16*)alloc((size_t)3072*1664*2);
  u16* whh0_b = (u16*)alloc((size_t)3072*1024*2);
  u16* wih1_b = (u16*)alloc((size_t)3072*1024*2);
  u16* whh1_b = (u16*)alloc((size_t)3072*1024*2);
  u16* wc0    = (u16*)alloc((size_t)1024*384*2);
  u16* wc1    = (u16*)alloc((size_t)1024*1024*2);
  u16* wc2    = (u16*)alloc((size_t)2048*1024*2);
  u16* w0k    = (u16*)alloc((size_t)256*896*2);
  u16* w1k    = (u16*)alloc((size_t)256*1280*2);
  u16* w2k    = (u16*)alloc((size_t)256*1024*2);
  u16* w3k    = (u16*)alloc((size_t)256*256*2);
  u16* wpT    = (u16*)alloc((size_t)1024*256*2);
  u16* wpg    = (u16*)alloc((size_t)256*1024*2);
  u16* Wdpg   = (u16*)alloc((size_t)1024*1024*2);
  u16* Wgpg   = (u16*)alloc((size_t)3072*1024*2);
  float* Sp = (float*)alloc(256*4);   float* Bp = (float*)alloc(256*4);
  float* S1 = (float*)alloc(1024*4);  float* B1 = (float*)alloc(1024*4);
  float* S2 = (float*)alloc(3072*4);  float* B2 = (float*)alloc(3072*4);
  float* vX = (float*)alloc(1024*4);  float* vG = (float*)alloc(3072*4);
  // sequences / state
  u16* aud_seq = (u16*)alloc((size_t)540*32*256*2);
  u16* lxm_b   = (u16*)alloc((size_t)18*32*128*2);
  u16* xc      = (u16*)alloc((size_t)32*384*2);
  u16* xc0     = (u16*)alloc((size_t)32*640*2);
  u16* ci1     = (u16*)alloc((size_t)32*1024*2);
  u16* ci2     = (u16*)alloc((size_t)32*1024*2);
  float* hraw  = (float*)alloc((size_t)32*2048*4);
  u16* h0i     = (u16*)alloc((size_t)32*1024*2);
  u16* h1i     = (u16*)alloc((size_t)32*1024*2);
  float* h0f   = (float*)alloc((size_t)32*1024*4);
  float* h1f   = (float*)alloc((size_t)32*1024*4);
  u16* pre_mo  = (u16*)alloc((size_t)32*256*2);
  float* GxR   = (float*)alloc((size_t)8*32*3072*4);
  float* XalR  = (float*)alloc((size_t)8*32*1024*4);
  float* GalR  = (float*)alloc((size_t)8*32*3072*4);
  int* cnt     = (int*)alloc((size_t)4*544*16*4);
  // encoder transients (dead before decode) -- rings alias this region
  char* enc_base = base + off;
  u16* O0   = (u16*)alloc((size_t)48384*256*2);
  u16* O1   = (u16*)alloc((size_t)46080*256*2);
  u16* O2   = (u16*)alloc((size_t)23040*256*2);
  float* O3 = (float*)alloc((size_t)23040*256*4);
  u16* Abuf = (u16*)alloc((size_t)23040*1280*2);
  // composition temps alias Abuf (free after conv GEMMs)
  float* Wdp_f = (float*)Abuf;                                  // 4 MB
  float* Wgp_f = (float*)((char*)Abuf + (size_t)1024*1024*4 + 256);  // 12.6 MB
  // rings alias the encoder region (<=110 MB of its 136 MB)
  u16* embR     = (u16*)enc_base;                  // 541 slots x 64 KB
  u16* h0R      = embR + (size_t)541*32768;        // 540 slots x 64 KB
  u16* h1R      = h0R + (size_t)540*32768;         // 540 slots x 64 KB
  float* statsR = (float*)(h1R + (size_t)540*32768); // 540 slots x 16 KB
  (void)ws_size; (void)in_sizes; (void)n_in; (void)out_size;

  const float* aud = (const float*)d_in[I_AUD];
  const float* mo  = (const float*)d_in[I_MO];
  const float* lxm = (const float*)d_in[I_LXM];
  float* out = (float*)d_out;

  auto cdiv = [](long long a, long long b)->int{ return (int)((a + b - 1) / b); };
  auto cvt = [&](int idx, u16* dst, int n){
    f2b_k<<<cdiv(n,256), 256, 0, stream>>>((const float*)d_in[idx], dst, n);
  };

  // ---- weight conversion ----
  cvt(I_DECW, wd_b,   1024*640);
  cvt(I_WIH0, wih0_b, 3072*1664);
  cvt(I_WHH0, whh0_b, 3072*1024);
  cvt(I_WIH1, wih1_b, 3072*1024);
  cvt(I_WHH1, whh1_b, 3072*1024);
  cvt(I_CIW0, wc0,    1024*384);
  cvt(I_CIW1, wc1,    1024*1024);
  cvt(I_CIW2, wc2,    2048*1024);
  cvt(I_AEW0, w0k,    256*896);
  cvt(I_AEW1, w1k,    256*1280);
  cvt(I_AEW2, w2k,    256*1024);
  cvt(I_AEW3, w3k,    256*256);

  // ---- encoder ----
  for (int c = 0; c < 2; ++c){
    int row0 = c * 24192;
    long long tot = (long long)24192 * 896;
    im2col0_k<<<cdiv(tot,256), 256, 0, stream>>>(aud, Abuf, row0, tot);
    gemm_bt<<<dim3(24192/64, 4), 256, 0, stream>>>(Abuf, 896, w0k, 896, (const float*)d_in[I_AEB0],
        O0 + (size_t)row0*256, 24192, 256, 896, GELU_FLG|BF16_FLG);
  }
  for (int c = 0; c < 2; ++c){
    int row0 = c * 23040;
    long long tot = (long long)23040 * 1280;
    im2col1_k<<<cdiv(tot,256), 256, 0, stream>>>(O0, Abuf, row0, tot);
    gemm_bt<<<dim3(23040/64, 4), 256, 0, stream>>>(Abuf, 1280, w1k, 1280, (const float*)d_in[I_AEB1],
        O1 + (size_t)row0*256, 23040, 256, 1280, GELU_FLG|BF16_FLG);
  }
  {
    long long tot = (long long)23040 * 1024;
    im2col2_k<<<cdiv(tot,256), 256, 0, stream>>>(O1, Abuf, 0, tot);
    gemm_bt<<<dim3(23040/64, 4), 256, 0, stream>>>(Abuf, 1024, w2k, 1024, (const float*)d_in[I_AEB2],
        O2, 23040, 256, 1024, GELU_FLG|BF16_FLG);
  }
  gemm_bt<<<dim3(23040/64, 4), 256, 0, stream>>>(O2, 256, w3k, 256, (const float*)d_in[I_AEB3],
      O3, 23040, 256, 256, GELU_FLG);
  enc_ln_k<<<4320, 256, 0, stream>>>(O3, (const float*)d_in[I_AELNG], (const float*)d_in[I_AELNB], aud_seq);

  // ---- lxm + cell-init chain ----
  lxm_g_k<<<cdiv(18*32*128,256), 256, 0, stream>>>(lxm, lxm_b);
  gather_xc_k<<<cdiv(32*384,256), 256, 0, stream>>>(mo, lxm, xc, pre_mo);
  gemm_bt<<<dim3(1,16), 256, 0, stream>>>(xc, 384, wc0, 384, (const float*)d_in[I_CIB0],
      ci1, 32, 1024, 384, GELU_FLG|BF16_FLG);
  gemm_bt<<<dim3(1,16), 256, 0, stream>>>(ci1, 1024, wc1, 1024, (const float*)d_in[I_CIB1],
      ci2, 32, 1024, 1024, GELU_FLG|BF16_FLG);
  gemm_bt<<<dim3(1,32), 256, 0, stream>>>(ci2, 1024, wc2, 1024, (const float*)d_in[I_CIB2],
      hraw, 32, 2048, 1024, 0);
  split_h_k<<<cdiv(32*1024,256), 256, 0, stream>>>(hraw, h0i, h1i, h0f, h1f);

  // ---- composition precompute ----
  t_wpT_k<<<cdiv(1024*256,256), 256, 0, stream>>>((const float*)d_in[I_PREDW], wpT);
  gemm_bt<<<dim3(16,16), 256, 0, stream>>>(wd_b, 640, wpT, 256, nullptr, Wdp_f, 1024, 1024, 256, 0);
  gemm_bt<<<dim3(48,16), 256, 0, stream>>>(wih0_b + 1024, 1664, wpT, 256, nullptr, Wgp_f, 3072, 1024, 256, 0);
  foldW_k<<<cdiv(1024,4), 256, 0, stream>>>(Wdp_f, (const float*)d_in[I_LNG], (const float*)d_in[I_LNB],
      nullptr, Wdpg, S1, B1, 1024);
  foldW_k<<<cdiv(3072,4), 256, 0, stream>>>(Wgp_f, (const float*)d_in[I_LNG], (const float*)d_in[I_LNB],
      nullptr, Wgpg, S2, B2, 3072);
  foldW_k<<<cdiv(256,4), 256, 0, stream>>>((const float*)d_in[I_PREDW], (const float*)d_in[I_LNG],
      (const float*)d_in[I_LNB], (const float*)d_in[I_PREDB], wpg, Sp, Bp, 256);
  vfold_k<<<cdiv(1024,4), 256, 0, stream>>>((const float*)d_in[I_DECW], 640, 0,
      (const float*)d_in[I_PREDB], (const float*)d_in[I_DECB], vX, 1024);
  vfold_k<<<cdiv(3072,4), 256, 0, stream>>>((const float*)d_in[I_WIH0], 1664, 1024,
      (const float*)d_in[I_PREDB], nullptr, vG, 3072);

  // ---- t=0 boot values: emb_0 (ring slot 0) and Gx_0 (GxR slot 0) ----
  build_xc0_k<<<cdiv(32*640,256), 256, 0, stream>>>(pre_mo, aud_seq, lxm_b, xc0);
  gemm_bt<<<dim3(1,16), 256, 0, stream>>>(xc0, 640, wd_b, 640, (const float*)d_in[I_DECB],
      embR, 32, 1024, 640, GELU_FLG|BF16_FLG);
  gemm_bt<<<dim3(1,48), 256, 0, stream>>>(xc0, 640, wih0_b + 1024, 1664, nullptr,
      GxR, 32, 3072, 640, 0);

  hipMemsetAsync(cnt, 0, (size_t)4*544*16*4, stream);

  // ---- persistent dataflow decoder ----
  DecArgs da;
  da.aud_seq = aud_seq; da.lxm_b = lxm_b;
  da.wih0 = wih0_b; da.whh0 = whh0_b; da.wih1 = wih1_b; da.whh1 = whh1_b; da.wd = wd_b;
  da.wpg = wpg; da.Wdpg = Wdpg; da.Wgpg = Wgpg;
  da.Sp = Sp; da.Bp = Bp; da.S1 = S1; da.B1 = B1; da.S2 = S2; da.B2 = B2; da.vX = vX; da.vG = vG;
  da.bih0 = (const float*)d_in[I_BIH0]; da.bhh0 = (const float*)d_in[I_BHH0];
  da.bih1 = (const float*)d_in[I_BIH1]; da.bhh1 = (const float*)d_in[I_BHH1];
  da.h0init = h0i; da.h1init = h1i;
  da.embR = embR; da.h0R = h0R; da.h1R = h1R; da.statsR = statsR;
  da.GxR = GxR; da.XalR = XalR; da.GalR = GalR;
  da.h0f = h0f; da.h1f = h1f;
  da.out = out; da.cnt = cnt;
  decode_k<<<dim3(NBLK), dim3(256), 0, stream>>>(da);
}

// Round 8
// 20838.516 us; speedup vs baseline: 1.1745x; 1.1745x over previous
//
#include <hip/hip_runtime.h>

// ---------------------------------------------------------------------------
// MotionGenerator RNN for MI355X (gfx950).
//  - encoder: im2col + bf16 MFMA GEMM (weights are [out,in] == [N,K] B^T layout)
//  - decoder: weight-stationary persistent DATAFLOW kernel, 213 blocks.
//    Sync = contention-free: producer-private epoch slots -> 1 watcher block
//    (one wave per group, 64-lane slot scan + __all) -> per-consumer flag
//    lines (1 writer, 1 reader each). No RMW chains, no shared poll lines.
//    Activations ride never-reused rings (emb/h0/h1/stats full 540-slot;
//    Gx/Xal/Gal mod-8, flag-gated reuse). Producers store uncached (sc0 sc1);
//    consumers read fresh ring addresses CACHED (per-XCD L2 multicast).
// ---------------------------------------------------------------------------

typedef unsigned short u16;
typedef __attribute__((ext_vector_type(8))) short short8;
typedef __attribute__((ext_vector_type(4))) float f32x4;

#define GELU_FLG 1
#define BF16_FLG 2
#define NBLK 213
#define DEC_STEPS 540

__device__ __forceinline__ u16 f2b(float f){
  union { float f; unsigned u; } c; c.f = f;
  return (u16)((c.u + 0x7fffu + ((c.u >> 16) & 1u)) >> 16);   // RNE
}
__device__ __forceinline__ short8 ld8(const u16* p){
  return *reinterpret_cast<const short8*>(p);
}
// coherent (agent-scope, cache-bypass) accessors for cross-block data
__device__ __forceinline__ float ldfc(const float* p){
  return __hip_atomic_load(p, __ATOMIC_RELAXED, __HIP_MEMORY_SCOPE_AGENT);
}
__device__ __forceinline__ void stfc(float* p, float v){
  __hip_atomic_store(p, v, __ATOMIC_RELAXED, __HIP_MEMORY_SCOPE_AGENT);
}
__device__ __forceinline__ void stu32c(u16* p, unsigned v){
  __hip_atomic_store((unsigned*)p, v, __ATOMIC_RELAXED, __HIP_MEMORY_SCOPE_AGENT);
}
__device__ __forceinline__ void st16c(u16* p, unsigned v){
  asm volatile("global_store_short %0, %1, off sc0 sc1" :: "v"(p), "v"(v) : "memory");
}
__device__ __forceinline__ f32x4 mfma16(short8 a, short8 b, f32x4 c){
  return __builtin_amdgcn_mfma_f32_16x16x32_bf16(a, b, c, 0, 0, 0);
}
__device__ __forceinline__ float gelu_f(float x){
  return 0.5f * x * (1.f + erff(x * 0.70710678118654752f));   // exact gelu
}
__device__ __forceinline__ float sigmoid_f(float x){
  return 1.f / (1.f + __expf(-x));
}
__device__ __forceinline__ float tanh_f(float x){
  float e = __expf(-2.f * x);
  return (1.f - e) / (1.f + e);
}

// ---------------- elementwise / gather kernels ----------------

__global__ void f2b_k(const float* __restrict__ s, u16* __restrict__ d, int n){
  int i = blockIdx.x * 256 + threadIdx.x;
  if (i < n) d[i] = f2b(s[i]);
}

__global__ void gather_xc_k(const float* __restrict__ mo, const float* __restrict__ lxm,
                            u16* __restrict__ xc, u16* __restrict__ pre_mo){
  int i = blockIdx.x * 256 + threadIdx.x;
  if (i >= 32 * 384) return;
  int n = i / 384, c = i - n * 384;
  float v = (c < 256) ? mo[(size_t)(n * 256 + c) * 600 + 29]
                      : lxm[(size_t)(n * 128 + (c - 256)) * 20];
  u16 h = f2b(v);
  xc[i] = h;
  if (c < 256) pre_mo[n * 256 + c] = h;
}

__global__ void lxm_g_k(const float* __restrict__ lxm, u16* __restrict__ o){
  int i = blockIdx.x * 256 + threadIdx.x;
  if (i >= 18 * 32 * 128) return;
  int c = i & 127, rest = i >> 7;
  int n = rest & 31, b = rest >> 5;
  o[i] = f2b(lxm[(size_t)(n * 128 + c) * 20 + 1 + b]);
}

__global__ void split_h_k(const float* __restrict__ hraw, u16* __restrict__ h0, u16* __restrict__ h1,
                          float* __restrict__ h0f, float* __restrict__ h1f){
  int i = blockIdx.x * 256 + threadIdx.x;
  if (i >= 32 * 1024) return;
  int n = i >> 10, c = i & 1023;
  float a = hraw[(size_t)n * 2048 + c];
  float b = hraw[(size_t)n * 2048 + 1024 + c];
  h0[i] = f2b(a); h1[i] = f2b(b);
  h0f[i] = a;     h1f[i] = b;
}

__global__ void build_xc0_k(const u16* __restrict__ pre_mo, const u16* __restrict__ aud_seq,
                            const u16* __restrict__ lxm_b, u16* __restrict__ xc0){
  int i = blockIdx.x * 256 + threadIdx.x;
  if (i >= 32 * 640) return;
  int n = i / 640, c = i - n * 640;
  u16 v;
  if (c < 256) v = pre_mo[n * 256 + c];
  else if (c < 512) v = aud_seq[n * 256 + (c - 256)];
  else v = lxm_b[n * 128 + (c - 512)];
  xc0[i] = v;
}

__global__ void t_wpT_k(const float* __restrict__ wp, u16* __restrict__ wpT){
  int i = blockIdx.x * 256 + threadIdx.x;
  if (i >= 1024 * 256) return;
  int h = i >> 8, j = i & 255;
  wpT[i] = f2b(wp[(size_t)j * 1024 + h]);
}

// fold LN gain/bias into a [R x 1024] matrix that acts on LN(h1)
__global__ void foldW_k(const float* __restrict__ src, const float* __restrict__ g,
                        const float* __restrict__ b, const float* __restrict__ addb,
                        u16* __restrict__ Wg, float* __restrict__ S, float* __restrict__ B, int R){
  int row = blockIdx.x * 4 + (threadIdx.x >> 6);
  if (row >= R) return;
  int lane = threadIdx.x & 63;
  const float* sr = src + (size_t)row * 1024;
  float s = 0.f, bb = 0.f;
  #pragma unroll
  for (int k = 0; k < 16; ++k){
    int c = lane + k * 64;
    float w = sr[c], gw = w * g[c];
    Wg[(size_t)row * 1024 + c] = f2b(gw);
    s += gw; bb += w * b[c];
  }
  #pragma unroll
  for (int m = 1; m < 64; m <<= 1){ s += __shfl_xor(s, m); bb += __shfl_xor(bb, m); }
  if (lane == 0){ S[row] = s; B[row] = bb + (addb ? addb[row] : 0.f); }
}

// v[row] = base[row] + sum_{j<256} W[row*ldw + off + j] * pb[j]
__global__ void vfold_k(const float* __restrict__ W, int ldw, int off, const float* __restrict__ pb,
                        const float* __restrict__ base, float* __restrict__ v, int R){
  int row = blockIdx.x * 4 + (threadIdx.x >> 6);
  if (row >= R) return;
  int lane = threadIdx.x & 63;
  const float* wr = W + (size_t)row * ldw + off;
  float s = 0.f;
  #pragma unroll
  for (int k = 0; k < 4; ++k){ int j = lane + k * 64; s += wr[j] * pb[j]; }
  #pragma unroll
  for (int m = 1; m < 64; m <<= 1) s += __shfl_xor(s, m);
  if (lane == 0) v[row] = s + (base ? base[row] : 0.f);
}

// ---------------- im2col kernels ----------------

__global__ void im2col0_k(const float* __restrict__ aud, u16* __restrict__ A, int row0, long long tot){
  long long i = (long long)blockIdx.x * 256 + threadIdx.x;
  if (i >= tot) return;
  int k = (int)(i % 896);
  int row = row0 + (int)(i / 896);
  int ci = k / 7, kk = k - ci * 7;
  int p = row % 84, bn = row / 84;
  int b = bn >> 5, n = bn & 31;
  A[i] = f2b(aud[(size_t)(n * 128 + ci) * 600 + b * 30 + p + kk]);
}

__global__ void im2col1_k(const u16* __restrict__ O0, u16* __restrict__ A, int row0, long long tot){
  long long i = (long long)blockIdx.x * 256 + threadIdx.x;
  if (i >= tot) return;
  int k = (int)(i % 1280);
  int row = row0 + (int)(i / 1280);
  int ci = k / 5, kk = k - ci * 5;
  int p = row % 80, bn = row / 80;
  A[i] = O0[(size_t)(bn * 84 + p + kk) * 256 + ci];
}

__global__ void im2col2_k(const u16* __restrict__ O1, u16* __restrict__ A, int row0, long long tot){
  long long i = (long long)blockIdx.x * 256 + threadIdx.x;
  if (i >= tot) return;
  int k = (int)(i & 1023);
  int row = row0 + (int)(i >> 10);
  int ci = k >> 2, kk = k & 3;
  int p = row % 40, bn = row / 40;
  int pos = 2 * p - 1 + kk;                      // stride 2, pad 1
  A[i] = (pos >= 0 && pos < 80) ? O1[(size_t)(bn * 80 + pos) * 256 + ci] : (u16)0;
}

// ---------------- GEMM: C[M,N] = A[M,K] @ W[N,K]^T  (bf16 MFMA) ----------------

__global__ void gemm_bt(const u16* __restrict__ A, int lda,
                        const u16* __restrict__ W, int ldw, const float* __restrict__ bias,
                        void* __restrict__ outp, int M, int N, int K, int flags){
  const int lane = threadIdx.x & 63, widx = threadIdx.x >> 6;
  const int m0 = blockIdx.x * 64 + widx * 16;
  if (m0 >= M) return;
  const int n0 = blockIdx.y * 64;
  const int r = lane & 15, g4 = lane >> 4;
  const u16* arow = A + (size_t)(m0 + r) * lda + g4 * 8;
  const u16* wrow = W + (size_t)(n0 + r) * ldw + g4 * 8;
  f32x4 acc[4];
  const f32x4 FZ = {0.f, 0.f, 0.f, 0.f};
  acc[0] = FZ; acc[1] = FZ; acc[2] = FZ; acc[3] = FZ;
  for (int k = 0; k < K; k += 32){
    short8 a = ld8(arow + k);
    #pragma unroll
    for (int j = 0; j < 4; ++j)
      acc[j] = mfma16(a, ld8(wrow + (size_t)j * 16 * ldw + k), acc[j]);
  }
  #pragma unroll
  for (int j = 0; j < 4; ++j){
    int col = n0 + j * 16 + r;
    float bv = bias ? bias[col] : 0.f;
    #pragma unroll
    for (int q = 0; q < 4; ++q){
      int row = m0 + g4 * 4 + q;
      float v = acc[j][q] + bv;
      if (flags & GELU_FLG) v = gelu_f(v);
      if (flags & BF16_FLG) ((u16*)outp)[(size_t)row * N + col] = f2b(v);
      else                  ((float*)outp)[(size_t)row * N + col] = v;
    }
  }
}

// ---------------- encoder LayerNorm -> aud_seq (bf16) ----------------

__global__ void enc_ln_k(const float* __restrict__ O3, const float* __restrict__ g,
                         const float* __restrict__ bb, u16* __restrict__ aud_seq){
  int rid = blockIdx.x * 4 + (threadIdx.x >> 6);
  int lane = threadIdx.x & 63;
  int b = rid / 960, rem = rid - b * 960;
  int p2 = rem >> 5, n = rem & 31;
  int orow = (b * 32 + n) * 40 + p2;
  const float4 v = *reinterpret_cast<const float4*>(O3 + (size_t)orow * 256 + lane * 4);
  float s  = v.x + v.y + v.z + v.w;
  float s2 = v.x * v.x + v.y * v.y + v.z * v.z + v.w * v.w;
  #pragma unroll
  for (int m = 1; m < 64; m <<= 1){ s += __shfl_xor(s, m); s2 += __shfl_xor(s2, m); }
  float mu = s * (1.f / 256.f);
  float var = s2 * (1.f / 256.f) - mu * mu;
  float rs = rsqrtf(var + 1e-5f);
  int c = lane * 4;
  u16* dst = aud_seq + (size_t)rid * 256 + c;
  dst[0] = f2b((v.x - mu) * rs * g[c + 0] + bb[c + 0]);
  dst[1] = f2b((v.y - mu) * rs * g[c + 1] + bb[c + 1]);
  dst[2] = f2b((v.z - mu) * rs * g[c + 2] + bb[c + 2]);
  dst[3] = f2b((v.w - mu) * rs * g[c + 3] + bb[c + 3]);
}

// ---------------- persistent weight-stationary dataflow decoder ----------------

struct DecArgs {
  const u16 *aud_seq, *lxm_b;
  const u16 *wih0, *whh0, *wih1, *whh1, *wd;       // bf16 blobs
  const u16 *wpg, *Wdpg, *Wgpg;                    // LN-folded PE weights
  const float *Sp, *Bp, *S1, *B1, *S2, *B2, *vX, *vG;
  const float *bih0, *bhh0, *bih1, *bhh1;
  const u16 *h0init, *h1init;
  u16 *embR, *h0R, *h1R;                 // rings: slot t = 32x1024 bf16 (64 KB)
  float *statsR;                         // ring:  slot t = [64 blk][64] f32
  float *GxR, *XalR, *GalR;              // mod-8 rings (flag-gated reuse)
  float *h0f, *h1f, *out;
  int *sync;                             // slots[4][128][16] + flags[4][256][16]
};

// producer: drain stores, then publish epoch on own private slot line
__device__ __forceinline__ void sigslot(int* slot, int ep){
  asm volatile("s_waitcnt vmcnt(0)" ::: "memory");
  __syncthreads();
  if (threadIdx.x == 0)
    __hip_atomic_store(slot, ep, __ATOMIC_RELAXED, __HIP_MEMORY_SCOPE_AGENT);
}
// consumer: poll own flag line with one thread
__device__ __forceinline__ void waitflag(const int* flag, int tgt){
  if (threadIdx.x == 0){
    while (__hip_atomic_load(flag, __ATOMIC_RELAXED, __HIP_MEMORY_SCOPE_AGENT) < tgt)
      __builtin_amdgcn_s_sleep(1);
  }
  __syncthreads();
}

__global__ __launch_bounds__(256, 1) void decode_k(DecArgs A){
  const int tid = threadIdx.x;
  const int lane = tid & 63, q = tid >> 6;
  const int r = lane & 15, g4 = lane >> 4;
  const int blk = blockIdx.x;
  __shared__ float lds[4][4][32][17];
  const f32x4 FZ = {0.f, 0.f, 0.f, 0.f};
  // sync layout (ints): slots: group g at g*128*16; flags: group g at (512+g*256)*16
  int* const slotH0 = A.sync;
  int* const slotH1 = A.sync + 128 * 16;
  int* const slotPE = A.sync + 256 * 16;
  int* const slotAL = A.sync + 384 * 16;
  int* const flagH0 = A.sync + 512 * 16;
  int* const flagH1 = A.sync + 768 * 16;
  int* const flagPE = A.sync + 1024 * 16;
  int* const flagAL = A.sync + 1280 * 16;

  if (blk < 64){
    // ---------------- L0: h0 producer (wih0_e + whh0 resident) ----------------
    const int c0 = blk * 16;
    const int kq = q * 256;
    int* const myFpe = flagPE + blk * 16;
    int* const myFh0 = flagH0 + blk * 16;
    int* const mySlot = slotH0 + blk * 16;
    short8 we[24], wh[24];
    #pragma unroll
    for (int g = 0; g < 3; ++g)
      #pragma unroll
      for (int ch = 0; ch < 8; ++ch){
        we[g * 8 + ch] = ld8(A.wih0 + (size_t)(g * 1024 + c0 + r) * 1664 + kq + ch * 32 + g4 * 8);
        wh[g * 8 + ch] = ld8(A.whh0 + (size_t)(g * 1024 + c0 + r) * 1024 + kq + ch * 32 + g4 * 8);
      }
    const int n_c = tid >> 3;
    const int cc0 = (tid & 7) * 2;
    const int colA = c0 + cc0, colB = colA + 1;
    const float bi_r[2] = {A.bih0[colA], A.bih0[colB]};
    const float bi_z[2] = {A.bih0[1024 + colA], A.bih0[1024 + colB]};
    const float bi_n[2] = {A.bih0[2048 + colA], A.bih0[2048 + colB]};
    const float bh_r[2] = {A.bhh0[colA], A.bhh0[colB]};
    const float bh_z[2] = {A.bhh0[1024 + colA], A.bhh0[1024 + colB]};
    const float bh_n[2] = {A.bhh0[2048 + colA], A.bhh0[2048 + colB]};
    f32x4 ar[2], az[2], ani[2], anh[2];
    // pre-loop: gh0 on initial h0
    ar[0] = FZ; ar[1] = FZ; az[0] = FZ; az[1] = FZ; ani[0] = FZ; ani[1] = FZ; anh[0] = FZ; anh[1] = FZ;
    #pragma unroll
    for (int ch = 0; ch < 8; ++ch){
      short8 a0 = ld8(A.h0init + r * 1024 + kq + ch * 32 + g4 * 8);
      short8 a1 = ld8(A.h0init + (16 + r) * 1024 + kq + ch * 32 + g4 * 8);
      ar[0] = mfma16(a0, wh[ch], ar[0]);        ar[1] = mfma16(a1, wh[ch], ar[1]);
      az[0] = mfma16(a0, wh[8 + ch], az[0]);    az[1] = mfma16(a1, wh[8 + ch], az[1]);
      anh[0] = mfma16(a0, wh[16 + ch], anh[0]); anh[1] = mfma16(a1, wh[16 + ch], anh[1]);
    }
    #pragma unroll 1
    for (int t = 0; t < DEC_STEPS; ++t){
      if (t > 0) waitflag(myFpe, t);                  // PE step t-1 done: emb[t], Gx[t]
      const u16*  embT = A.embR + (size_t)t * 32768;
      u16*        h0T  = A.h0R  + (size_t)t * 32768;
      const float* GxT = A.GxR + (size_t)(t & 7) * 98304;
      float pgr[2], pgz[2], pgn[2], phf[2];
      #pragma unroll
      for (int e = 0; e < 2; ++e){
        int col = c0 + cc0 + e;
        pgr[e] = ldfc(GxT + n_c * 3072 + col);
        pgz[e] = ldfc(GxT + n_c * 3072 + 1024 + col);
        pgn[e] = ldfc(GxT + n_c * 3072 + 2048 + col);
        phf[e] = A.h0f[n_c * 1024 + col];
      }
      #pragma unroll
      for (int ch = 0; ch < 8; ++ch){
        short8 a0 = ld8(embT + r * 1024 + kq + ch * 32 + g4 * 8);
        short8 a1 = ld8(embT + (16 + r) * 1024 + kq + ch * 32 + g4 * 8);
        ar[0] = mfma16(a0, we[ch], ar[0]);        ar[1] = mfma16(a1, we[ch], ar[1]);
        az[0] = mfma16(a0, we[8 + ch], az[0]);    az[1] = mfma16(a1, we[8 + ch], az[1]);
        ani[0] = mfma16(a0, we[16 + ch], ani[0]); ani[1] = mfma16(a1, we[16 + ch], ani[1]);
      }
      #pragma unroll
      for (int m = 0; m < 2; ++m)
        #pragma unroll
        for (int j = 0; j < 4; ++j){
          int row = m * 16 + g4 * 4 + j;
          lds[q][0][row][r] = ar[m][j];
          lds[q][1][row][r] = az[m][j];
          lds[q][2][row][r] = ani[m][j];
          lds[q][3][row][r] = anh[m][j];
        }
      __syncthreads();
      float hv2[2];
      #pragma unroll
      for (int e = 0; e < 2; ++e){
        int cc = cc0 + e, col = c0 + cc;
        float sr = bi_r[e] + bh_r[e] + pgr[e];
        float sz = bi_z[e] + bh_z[e] + pgz[e];
        float si = bi_n[e] + pgn[e];
        float sh = bh_n[e];
        #pragma unroll
        for (int qq = 0; qq < 4; ++qq){
          sr += lds[qq][0][n_c][cc]; sz += lds[qq][1][n_c][cc];
          si += lds[qq][2][n_c][cc]; sh += lds[qq][3][n_c][cc];
        }
        float rg = sigmoid_f(sr), zg = sigmoid_f(sz);
        float ng = tanh_f(si + rg * sh);
        float hv = (1.f - zg) * ng + zg * phf[e];
        A.h0f[n_c * 1024 + col] = hv;            // private, cached
        hv2[e] = hv;
      }
      stu32c(h0T + n_c * 1024 + colA,
             (unsigned)f2b(hv2[0]) | ((unsigned)f2b(hv2[1]) << 16));
      __syncthreads();                           // lds reuse guard
      sigslot(mySlot, t + 1);
      waitflag(myFh0, t + 1);                    // full h0[t] for gh0-next
      ar[0] = FZ; ar[1] = FZ; az[0] = FZ; az[1] = FZ; ani[0] = FZ; ani[1] = FZ; anh[0] = FZ; anh[1] = FZ;
      #pragma unroll
      for (int ch = 0; ch < 8; ++ch){
        short8 a0 = ld8(h0T + r * 1024 + kq + ch * 32 + g4 * 8);
        short8 a1 = ld8(h0T + (16 + r) * 1024 + kq + ch * 32 + g4 * 8);
        ar[0] = mfma16(a0, wh[ch], ar[0]);        ar[1] = mfma16(a1, wh[ch], ar[1]);
        az[0] = mfma16(a0, wh[8 + ch], az[0]);    az[1] = mfma16(a1, wh[8 + ch], az[1]);
        anh[0] = mfma16(a0, wh[16 + ch], anh[0]); anh[1] = mfma16(a1, wh[16 + ch], anh[1]);
      }
    }
  } else if (blk < 128){
    // ---------------- L1: h1 producer (wih1 + whh1 resident) ----------------
    const int c0 = (blk - 64) * 16;
    const int kq = q * 256;
    int* const myFh0 = flagH0 + blk * 16;
    int* const myFh1 = flagH1 + blk * 16;
    int* const mySlot = slotH1 + (blk - 64) * 16;
    short8 wi[24], wh[24];
    #pragma unroll
    for (int g = 0; g < 3; ++g)
      #pragma unroll
      for (int ch = 0; ch < 8; ++ch){
        wi[g * 8 + ch] = ld8(A.wih1 + (size_t)(g * 1024 + c0 + r) * 1024 + kq + ch * 32 + g4 * 8);
        wh[g * 8 + ch] = ld8(A.whh1 + (size_t)(g * 1024 + c0 + r) * 1024 + kq + ch * 32 + g4 * 8);
      }
    const int n_c = tid >> 3;
    const int cc0 = (tid & 7) * 2;
    const int colA = c0 + cc0, colB = colA + 1;
    const float bi_r[2] = {A.bih1[colA], A.bih1[colB]};
    const float bi_z[2] = {A.bih1[1024 + colA], A.bih1[1024 + colB]};
    const float bi_n[2] = {A.bih1[2048 + colA], A.bih1[2048 + colB]};
    const float bh_r[2] = {A.bhh1[colA], A.bhh1[colB]};
    const float bh_z[2] = {A.bhh1[1024 + colA], A.bhh1[1024 + colB]};
    const float bh_n[2] = {A.bhh1[2048 + colA], A.bhh1[2048 + colB]};
    f32x4 ar[2], az[2], ani[2], anh[2];
    // pre-loop: gh1 on initial h1
    ar[0] = FZ; ar[1] = FZ; az[0] = FZ; az[1] = FZ; ani[0] = FZ; ani[1] = FZ; anh[0] = FZ; anh[1] = FZ;
    #pragma unroll
    for (int ch = 0; ch < 8; ++ch){
      short8 a0 = ld8(A.h1init + r * 1024 + kq + ch * 32 + g4 * 8);
      short8 a1 = ld8(A.h1init + (16 + r) * 1024 + kq + ch * 32 + g4 * 8);
      ar[0] = mfma16(a0, wh[ch], ar[0]);        ar[1] = mfma16(a1, wh[ch], ar[1]);
      az[0] = mfma16(a0, wh[8 + ch], az[0]);    az[1] = mfma16(a1, wh[8 + ch], az[1]);
      anh[0] = mfma16(a0, wh[16 + ch], anh[0]); anh[1] = mfma16(a1, wh[16 + ch], anh[1]);
    }
    #pragma unroll 1
    for (int t = 0; t < DEC_STEPS; ++t){
      waitflag(myFh0, t + 1);                    // h0[t] ready
      const u16* h0T = A.h0R + (size_t)t * 32768;
      u16*       h1T = A.h1R + (size_t)t * 32768;
      float phf[2];
      phf[0] = A.h1f[n_c * 1024 + colA];
      phf[1] = A.h1f[n_c * 1024 + colB];
      #pragma unroll
      for (int ch = 0; ch < 8; ++ch){
        short8 a0 = ld8(h0T + r * 1024 + kq + ch * 32 + g4 * 8);
        short8 a1 = ld8(h0T + (16 + r) * 1024 + kq + ch * 32 + g4 * 8);
        ar[0] = mfma16(a0, wi[ch], ar[0]);        ar[1] = mfma16(a1, wi[ch], ar[1]);
        az[0] = mfma16(a0, wi[8 + ch], az[0]);    az[1] = mfma16(a1, wi[8 + ch], az[1]);
        ani[0] = mfma16(a0, wi[16 + ch], ani[0]); ani[1] = mfma16(a1, wi[16 + ch], ani[1]);
      }
      #pragma unroll
      for (int m = 0; m < 2; ++m)
        #pragma unroll
        for (int j = 0; j < 4; ++j){
          int row = m * 16 + g4 * 4 + j;
          lds[q][0][row][r] = ar[m][j];
          lds[q][1][row][r] = az[m][j];
          lds[q][2][row][r] = ani[m][j];
          lds[q][3][row][r] = anh[m][j];
        }
      __syncthreads();
      float hv2[2];
      #pragma unroll
      for (int e = 0; e < 2; ++e){
        int cc = cc0 + e, col = c0 + cc;
        float sr = bi_r[e] + bh_r[e];
        float sz = bi_z[e] + bh_z[e];
        float si = bi_n[e];
        float sh = bh_n[e];
        #pragma unroll
        for (int qq = 0; qq < 4; ++qq){
          sr += lds[qq][0][n_c][cc]; sz += lds[qq][1][n_c][cc];
          si += lds[qq][2][n_c][cc]; sh += lds[qq][3][n_c][cc];
        }
        float rg = sigmoid_f(sr), zg = sigmoid_f(sz);
        float ng = tanh_f(si + rg * sh);
        float hv = (1.f - zg) * ng + zg * phf[e];
        A.h1f[n_c * 1024 + col] = hv;            // private, cached
        hv2[e] = hv;
      }
      stu32c(h1T + n_c * 1024 + colA,
             (unsigned)f2b(hv2[0]) | ((unsigned)f2b(hv2[1]) << 16));
      float sv = hv2[0] + hv2[1], sq = hv2[0] * hv2[0] + hv2[1] * hv2[1];
      sv += __shfl_xor(sv, 1); sq += __shfl_xor(sq, 1);
      sv += __shfl_xor(sv, 2); sq += __shfl_xor(sq, 2);
      sv += __shfl_xor(sv, 4); sq += __shfl_xor(sq, 4);
      if ((tid & 7) == 0){
        stfc(A.statsR + (size_t)t * 4096 + (blk - 64) * 64 + n_c, sv);
        stfc(A.statsR + (size_t)t * 4096 + (blk - 64) * 64 + 32 + n_c, sq);
      }
      __syncthreads();                           // lds reuse guard
      sigslot(mySlot, t + 1);
      waitflag(myFh1, t + 1);                    // full h1[t] for gh1-next
      ar[0] = FZ; ar[1] = FZ; az[0] = FZ; az[1] = FZ; ani[0] = FZ; ani[1] = FZ; anh[0] = FZ; anh[1] = FZ;
      #pragma unroll
      for (int ch = 0; ch < 8; ++ch){
        short8 a0 = ld8(h1T + r * 1024 + kq + ch * 32 + g4 * 8);
        short8 a1 = ld8(h1T + (16 + r) * 1024 + kq + ch * 32 + g4 * 8);
        ar[0] = mfma16(a0, wh[ch], ar[0]);        ar[1] = mfma16(a1, wh[ch], ar[1]);
        az[0] = mfma16(a0, wh[8 + ch], az[0]);    az[1] = mfma16(a1, wh[8 + ch], az[1]);
        anh[0] = mfma16(a0, wh[16 + ch], anh[0]); anh[1] = mfma16(a1, wh[16 + ch], anh[1]);
      }
    }
  } else if (blk < 196){
    // ---------------- PE: pred / emb_{t+1} / Gx_{t+1} on h1 (LN folded) ----------------
    const int tile = (blk - 128) * 4 + q;     // 0..271
    int* const myFh1 = flagH1 + blk * 16;
    int* const myFal = flagAL + blk * 16;
    int* const mySlot = slotPE + (blk - 128) * 16;
    int jt, c0;
    const u16* wsrc; const float *Sv, *Bv;
    if (tile < 16)      { jt = 0; c0 = tile * 16;        wsrc = A.wpg;  Sv = A.Sp; Bv = A.Bp; }
    else if (tile < 80) { jt = 1; c0 = (tile - 16) * 16; wsrc = A.Wdpg; Sv = A.S1; Bv = A.B1; }
    else                { jt = 2; c0 = (tile - 80) * 16; wsrc = A.Wgpg; Sv = A.S2; Bv = A.B2; }
    short8 w[32];
    #pragma unroll
    for (int ch = 0; ch < 32; ++ch)
      w[ch] = ld8(wsrc + (size_t)(c0 + r) * 1024 + ch * 32 + g4 * 8);
    const float Sc = Sv[c0 + r], Bc = Bv[c0 + r];
    const int col = c0 + r;
    #pragma unroll 1
    for (int t = 0; t < DEC_STEPS; ++t){
      waitflag(myFh1, t + 1);                    // h1[t] + stats[t] ready
      waitflag(myFal, t + 1);                    // Xal/Gal[t+1] ready
      const u16*   h1T = A.h1R + (size_t)t * 32768;
      const float* stT = A.statsR + (size_t)t * 4096;
      const int sl = (t + 1) & 7;
      float sacc = 0.f;
      #pragma unroll
      for (int b2 = 0; b2 < 64; ++b2) sacc += stT[b2 * 64 + lane];
      float muA[2][4], rsA[2][4];
      #pragma unroll
      for (int m = 0; m < 2; ++m)
        #pragma unroll
        for (int j = 0; j < 4; ++j){
          int n = m * 16 + g4 * 4 + j;
          float sv = __shfl(sacc, n), sq = __shfl(sacc, 32 + n);
          float mu = sv * (1.f / 1024.f);
          muA[m][j] = mu;
          rsA[m][j] = rsqrtf(sq * (1.f / 1024.f) - mu * mu + 1e-5f);
        }
      f32x4 a0 = FZ, a1 = FZ;
      #pragma unroll
      for (int ch = 0; ch < 32; ++ch){
        short8 x0 = ld8(h1T + r * 1024 + ch * 32 + g4 * 8);
        short8 x1 = ld8(h1T + (16 + r) * 1024 + ch * 32 + g4 * 8);
        a0 = mfma16(x0, w[ch], a0);
        a1 = mfma16(x1, w[ch], a1);
      }
      u16*   embN = A.embR + (size_t)(t + 1) * 32768;
      float* GxN  = A.GxR + (size_t)sl * 98304;
      const float* XalT = A.XalR + (size_t)sl * 32768;
      const float* GalT = A.GalR + (size_t)sl * 98304;
      #pragma unroll
      for (int m = 0; m < 2; ++m)
        #pragma unroll
        for (int j = 0; j < 4; ++j){
          int n = m * 16 + g4 * 4 + j;
          float acc = (m ? a1[j] : a0[j]);
          float v = rsA[m][j] * (acc - muA[m][j] * Sc) + Bc;
          if (jt == 0){
            A.out[(size_t)n * (256 * 540) + (size_t)col * 540 + t] = v;   // cached; kernel-end flush
          } else if (jt == 1){
            float pre = v + ldfc(XalT + n * 1024 + col);
            st16c(embN + n * 1024 + col, (unsigned)f2b(gelu_f(pre)));
          } else {
            stfc(GxN + n * 3072 + col, v + ldfc(GalT + n * 3072 + col));
          }
        }
      sigslot(mySlot, t + 1);
    }
  } else if (blk < 212){
    // ---------------- AL: audio/lxm partials for step t+1 ----------------
    const int wg = (blk - 196) * 4 + q;       // 0..63
    int* const myFpe = flagPE + blk * 16;
    int* const mySlot = slotAL + (blk - 196) * 16;
    const int at0 = wg * 4;
    short8 w[48];
    float vb[4];
    #pragma unroll
    for (int j = 0; j < 4; ++j){
      int at = at0 + j;
      if (at < 64){
        #pragma unroll
        for (int ch = 0; ch < 12; ++ch)
          w[j * 12 + ch] = ld8(A.wd + (size_t)(at * 16 + r) * 640 + 256 + ch * 32 + g4 * 8);
        vb[j] = A.vX[at * 16 + r];
      } else {
        #pragma unroll
        for (int ch = 0; ch < 12; ++ch)
          w[j * 12 + ch] = ld8(A.wih0 + (size_t)((at - 64) * 16 + r) * 1664 + 1280 + ch * 32 + g4 * 8);
        vb[j] = A.vG[(at - 64) * 16 + r];
      }
    }
    #pragma unroll 1
    for (int t = 0; t < DEC_STEPS; ++t){
      if (t >= 8) waitflag(myFpe, t - 7);            // slot (t+1)&7 free
      const int tn = t + 1;
      const int tread = (tn > 539) ? 539 : tn;
      const int bn = tread / 30;
      const int sl = tn & 7;
      float* XalW = A.XalR + (size_t)sl * 32768;
      float* GalW = A.GalR + (size_t)sl * 98304;
      short8 af0[12], af1[12];
      #pragma unroll
      for (int ch = 0; ch < 12; ++ch){
        int kk = ch * 32 + g4 * 8;
        if (ch < 8){
          af0[ch] = ld8(A.aud_seq + ((size_t)tread * 32 + r) * 256 + kk);
          af1[ch] = ld8(A.aud_seq + ((size_t)tread * 32 + 16 + r) * 256 + kk);
        } else {
          af0[ch] = ld8(A.lxm_b + ((size_t)bn * 32 + r) * 128 + kk - 256);
          af1[ch] = ld8(A.lxm_b + ((size_t)bn * 32 + 16 + r) * 128 + kk - 256);
        }
      }
      #pragma unroll
      for (int j = 0; j < 4; ++j){
        f32x4 c0a = FZ, c1a = FZ;
        #pragma unroll
        for (int ch = 0; ch < 12; ++ch){
          c0a = mfma16(af0[ch], w[j * 12 + ch], c0a);
          c1a = mfma16(af1[ch], w[j * 12 + ch], c1a);
        }
        int at = at0 + j;
        #pragma unroll
        for (int m = 0; m < 2; ++m)
          #pragma unroll
          for (int jj = 0; jj < 4; ++jj){
            int n = m * 16 + g4 * 4 + jj;
            float v = (m ? c1a[jj] : c0a[jj]) + vb[j];
            if (at < 64) stfc(XalW + n * 1024 + at * 16 + r, v);
            else         stfc(GalW + n * 3072 + (at - 64) * 16 + r, v);
          }
      }
      sigslot(mySlot, tn);
    }
  } else {
    // ---------------- watcher block: one wave per group ----------------
    // wave q: group q in {0:H0(64), 1:H1(64), 2:PE(68), 3:AL(16)}
    const int NPs[4] = {64, 64, 68, 16};
    const int NP = NPs[q];
    int* const slotG = A.sync + q * 128 * 16;
    int* const flagG = A.sync + (512 + q * 256) * 16;
    const int idx1 = (lane < NP) ? lane : 0;
    const int extra = NP - 64;                       // 4 for PE, else <=0
    #pragma unroll 1
    for (int t = 1; t <= DEC_STEPS; ++t){
      for (;;){
        int v = __hip_atomic_load(slotG + idx1 * 16, __ATOMIC_RELAXED, __HIP_MEMORY_SCOPE_AGENT);
        bool ok = (v >= t);
        if (extra > 0 && lane < extra){
          int v2 = __hip_atomic_load(slotG + (64 + lane) * 16, __ATOMIC_RELAXED, __HIP_MEMORY_SCOPE_AGENT);
          ok = ok && (v2 >= t);
        }
        if (__all(ok)) break;
        __builtin_amdgcn_s_sleep(1);
      }
      #pragma unroll 1
      for (int c = lane; c < NBLK; c += 64)
        __hip_atomic_store(flagG + c * 16, t, __ATOMIC_RELAXED, __HIP_MEMORY_SCOPE_AGENT);
    }
  }
}

// ---------------------------------------------------------------------------

extern "C" void kernel_launch(void* const* d_in, const int* in_sizes, int n_in,
                              void* d_out, int out_size, void* d_ws, size_t ws_size,
                              hipStream_t stream) {
  enum { I_AUD=0, I_MO=1, I_LXM=2, I_AEW0=3, I_AEB0=4, I_AEW1=5, I_AEB1=6, I_AEW2=7, I_AEB2=8,
         I_AEW3=9, I_AEB3=10, I_AELNG=11, I_AELNB=12, I_CIW0=13, I_CIB0=14, I_CIW1=15, I_CIB1=16,
         I_CIW2=17, I_CIB2=18, I_DECW=19, I_DECB=20, I_WIH0=21, I_WHH0=22, I_BIH0=23, I_BHH0=24,
         I_WIH1=25, I_WHH1=26, I_BIH1=27, I_BHH1=28, I_LNG=29, I_LNB=30, I_PREDW=31, I_PREDB=32 };

  char* base = (char*)d_ws;
  size_t off = 0;
  auto alloc = [&](size_t bytes)->void*{
    void* p = base + off;
    off += (bytes + 255) & ~(size_t)255;
    return p;
  };

  // bf16 weight blobs
  u16* wd_b   = (u16*)alloc((size_t)1024*640*2);
  u16* wih0_b = (u16*)alloc((size_t)3072*1664*2);
  u16* whh0_b = (u16*)alloc((size_t)3072*1024*2);
  u16* wih1_b = (u16*)alloc((size_t)3072*1024*2);
  u16* whh1_b = (u16*)alloc((size_t)3072*1024*2);
  u16* wc0    = (u16*)alloc((size_t)1024*384*2);
  u16* wc1    = (u16*)alloc((size_t)1024*1024*2);
  u16* wc2    = (u16*)alloc((size_t)2048*1024*2);
  u16* w0k    = (u16*)alloc((size_t)256*896*2);
  u16* w1k    = (u16*)alloc((size_t)256*1280*2);
  u16* w2k    = (u16*)alloc((size_t)256*1024*2);
  u16* w3k    = (u16*)alloc((size_t)256*256*2);
  u16* wpT    = (u16*)alloc((size_t)1024*256*2);
  u16* wpg    = (u16*)alloc((size_t)256*1024*2);
  u16* Wdpg   = (u16*)alloc((size_t)1024*1024*2);
  u16* Wgpg   = (u16*)alloc((size_t)3072*1024*2);
  float* Sp = (float*)alloc(256*4);   float* Bp = (float*)alloc(256*4);
  float* S1 = (float*)alloc(1024*4);  float* B1 = (float*)alloc(1024*4);
  float* S2 = (float*)alloc(3072*4);  float* B2 = (float*)alloc(3072*4);
  float* vX = (float*)alloc(1024*4);  float* vG = (float*)alloc(3072*4);
  // sequences / state
  u16* aud_seq = (u16*)alloc((size_t)540*32*256*2);
  u16* lxm_b   = (u16*)alloc((size_t)18*32*128*2);
  u16* xc      = (u16*)alloc((size_t)32*384*2);
  u16* xc0     = (u16*)alloc((size_t)32*640*2);
  u16* ci1     = (u16*)alloc((size_t)32*1024*2);
  u16* ci2     = (u16*)alloc((size_t)32*1024*2);
  float* hraw  = (float*)alloc((size_t)32*2048*4);
  u16* h0i     = (u16*)alloc((size_t)32*1024*2);
  u16* h1i     = (u16*)alloc((size_t)32*1024*2);
  float* h0f   = (float*)alloc((size_t)32*1024*4);
  float* h1f   = (float*)alloc((size_t)32*1024*4);
  u16* pre_mo  = (u16*)alloc((size_t)32*256*2);
  float* GxR   = (float*)alloc((size_t)8*32*3072*4);
  float* XalR  = (float*)alloc((size_t)8*32*1024*4);
  float* GalR  = (float*)alloc((size_t)8*32*3072*4);
  int* syncb   = (int*)alloc((size_t)1536*16*4);     // slots + flags (96 KB)
  // encoder transients (dead before decode) -- rings alias this region
  char* enc_base = base + off;
  u16* O0   = (u16*)alloc((size_t)48384*256*2);
  u16* O1   = (u16*)alloc((size_t)46080*256*2);
  u16* O2   = (u16*)alloc((size_t)23040*256*2);
  float* O3 = (float*)alloc((size_t)23040*256*4);
  u16* Abuf = (u16*)alloc((size_t)23040*1280*2);
  // composition temps alias Abuf (free after conv GEMMs)
  float* Wdp_f = (float*)Abuf;                                  // 4 MB
  float* Wgp_f = (float*)((char*)Abuf + (size_t)1024*1024*4 + 256);  // 12.6 MB
  // rings alias the encoder region (<=110 MB of its 136 MB)
  u16* embR     = (u16*)enc_base;                  // 541 slots x 64 KB
  u16* h0R      = embR + (size_t)541*32768;        // 540 slots x 64 KB
  u16* h1R      = h0R + (size_t)540*32768;         // 540 slots x 64 KB
  float* statsR = (float*)(h1R + (size_t)540*32768); // 540 slots x 16 KB
  (void)ws_size; (void)in_sizes; (void)n_in; (void)out_size;

  const float* aud = (const float*)d_in[I_AUD];
  const float* mo  = (const float*)d_in[I_MO];
  const float* lxm = (const float*)d_in[I_LXM];
  float* out = (float*)d_out;

  auto cdiv = [](long long a, long long b)->int{ return (int)((a + b - 1) / b); };
  auto cvt = [&](int idx, u16* dst, int n){
    f2b_k<<<cdiv(n,256), 256, 0, stream>>>((const float*)d_in[idx], dst, n);
  };

  // ---- weight conversion ----
  cvt(I_DECW, wd_b,   1024*640);
  cvt(I_WIH0, wih0_b, 3072*1664);
  cvt(I_WHH0, whh0_b, 3072*1024);
  cvt(I_WIH1, wih1_b, 3072*1024);
  cvt(I_WHH1, whh1_b, 3072*1024);
  cvt(I_CIW0, wc0,    1024*384);
  cvt(I_CIW1, wc1,    1024*1024);
  cvt(I_CIW2, wc2,    2048*1024);
  cvt(I_AEW0, w0k,    256*896);
  cvt(I_AEW1, w1k,    256*1280);
  cvt(I_AEW2, w2k,    256*1024);
  cvt(I_AEW3, w3k,    256*256);

  // ---- encoder ----
  for (int c = 0; c < 2; ++c){
    int row0 = c * 24192;
    long long tot = (long long)24192 * 896;
    im2col0_k<<<cdiv(tot,256), 256, 0, stream>>>(aud, Abuf, row0, tot);
    gemm_bt<<<dim3(24192/64, 4), 256, 0, stream>>>(Abuf, 896, w0k, 896, (const float*)d_in[I_AEB0],
        O0 + (size_t)row0*256, 24192, 256, 896, GELU_FLG|BF16_FLG);
  }
  for (int c = 0; c < 2; ++c){
    int row0 = c * 23040;
    long long tot = (long long)23040 * 1280;
    im2col1_k<<<cdiv(tot,256), 256, 0, stream>>>(O0, Abuf, row0, tot);
    gemm_bt<<<dim3(23040/64, 4), 256, 0, stream>>>(Abuf, 1280, w1k, 1280, (const float*)d_in[I_AEB1],
        O1 + (size_t)row0*256, 23040, 256, 1280, GELU_FLG|BF16_FLG);
  }
  {
    long long tot = (long long)23040 * 1024;
    im2col2_k<<<cdiv(tot,256), 256, 0, stream>>>(O1, Abuf, 0, tot);
    gemm_bt<<<dim3(23040/64, 4), 256, 0, stream>>>(Abuf, 1024, w2k, 1024, (const float*)d_in[I_AEB2],
        O2, 23040, 256, 1024, GELU_FLG|BF16_FLG);
  }
  gemm_bt<<<dim3(23040/64, 4), 256, 0, stream>>>(O2, 256, w3k, 256, (const float*)d_in[I_AEB3],
      O3, 23040, 256, 256, GELU_FLG);
  enc_ln_k<<<4320, 256, 0, stream>>>(O3, (const float*)d_in[I_AELNG], (const float*)d_in[I_AELNB], aud_seq);

  // ---- lxm + cell-init chain ----
  lxm_g_k<<<cdiv(18*32*128,256), 256, 0, stream>>>(lxm, lxm_b);
  gather_xc_k<<<cdiv(32*384,256), 256, 0, stream>>>(mo, lxm, xc, pre_mo);
  gemm_bt<<<dim3(1,16), 256, 0, stream>>>(xc, 384, wc0, 384, (const float*)d_in[I_CIB0],
      ci1, 32, 1024, 384, GELU_FLG|BF16_FLG);
  gemm_bt<<<dim3(1,16), 256, 0, stream>>>(ci1, 1024, wc1, 1024, (const float*)d_in[I_CIB1],
      ci2, 32, 1024, 1024, GELU_FLG|BF16_FLG);
  gemm_bt<<<dim3(1,32), 256, 0, stream>>>(ci2, 1024, wc2, 1024, (const float*)d_in[I_CIB2],
      hraw, 32, 2048, 1024, 0);
  split_h_k<<<cdiv(32*1024,256), 256, 0, stream>>>(hraw, h0i, h1i, h0f, h1f);

  // ---- composition precompute ----
  t_wpT_k<<<cdiv(1024*256,256), 256, 0, stream>>>((const float*)d_in[I_PREDW], wpT);
  gemm_bt<<<dim3(16,16), 256, 0, stream>>>(wd_b, 640, wpT, 256, nullptr, Wdp_f, 1024, 1024, 256, 0);
  gemm_bt<<<dim3(48,16), 256, 0, stream>>>(wih0_b + 1024, 1664, wpT, 256, nullptr, Wgp_f, 3072, 1024, 256, 0);
  foldW_k<<<cdiv(1024,4), 256, 0, stream>>>(Wdp_f, (const float*)d_in[I_LNG], (const float*)d_in[I_LNB],
      nullptr, Wdpg, S1, B1, 1024);
  foldW_k<<<cdiv(3072,4), 256, 0, stream>>>(Wgp_f, (const float*)d_in[I_LNG], (const float*)d_in[I_LNB],
      nullptr, Wgpg, S2, B2, 3072);
  foldW_k<<<cdiv(256,4), 256, 0, stream>>>((const float*)d_in[I_PREDW], (const float*)d_in[I_LNG],
      (const float*)d_in[I_LNB], (const float*)d_in[I_PREDB], wpg, Sp, Bp, 256);
  vfold_k<<<cdiv(1024,4), 256, 0, stream>>>((const float*)d_in[I_DECW], 640, 0,
      (const float*)d_in[I_PREDB], (const float*)d_in[I_DECB], vX, 1024);
  vfold_k<<<cdiv(3072,4), 256, 0, stream>>>((const float*)d_in[I_WIH0], 1664, 1024,
      (const float*)d_in[I_PREDB], nullptr, vG, 3072);

  // ---- t=0 boot values: emb_0 (ring slot 0) and Gx_0 (GxR slot 0) ----
  build_xc0_k<<<cdiv(32*640,256), 256, 0, stream>>>(pre_mo, aud_seq, lxm_b, xc0);
  gemm_bt<<<dim3(1,16), 256, 0, stream>>>(xc0, 640, wd_b, 640, (const float*)d_in[I_DECB],
      embR, 32, 1024, 640, GELU_FLG|BF16_FLG);
  gemm_bt<<<dim3(1,48), 256, 0, stream>>>(xc0, 640, wih0_b + 1024, 1664, nullptr,
      GxR, 32, 3072, 640, 0);

  hipMemsetAsync(syncb, 0, (size_t)1536*16*4, stream);

  // ---- persistent dataflow decoder ----
  DecArgs da;
  da.aud_seq = aud_seq; da.lxm_b = lxm_b;
  da.wih0 = wih0_b; da.whh0 = whh0_b; da.wih1 = wih1_b; da.whh1 = whh1_b; da.wd = wd_b;
  da.wpg = wpg; da.Wdpg = Wdpg; da.Wgpg = Wgpg;
  da.Sp = Sp; da.Bp = Bp; da.S1 = S1; da.B1 = B1; da.S2 = S2; da.B2 = B2; da.vX = vX; da.vG = vG;
  da.bih0 = (const float*)d_in[I_BIH0]; da.bhh0 = (const float*)d_in[I_BHH0];
  da.bih1 = (const float*)d_in[I_BIH1]; da.bhh1 = (const float*)d_in[I_BHH1];
  da.h0init = h0i; da.h1init = h1i;
  da.embR = embR; da.h0R = h0R; da.h1R = h1R; da.statsR = statsR;
  da.GxR = GxR; da.XalR = XalR; da.GalR = GalR;
  da.h0f = h0f; da.h1f = h1f;
  da.out = out; da.sync = syncb;
  decode_k<<<dim3(NBLK), dim3(256), 0, stream>>>(da);
}

// Round 9
// 8684.460 us; speedup vs baseline: 2.8183x; 2.3995x over previous
//
#include <hip/hip_runtime.h>

// ---------------------------------------------------------------------------
// MotionGenerator RNN for MI355X (gfx950).
//  - encoder: im2col + bf16 MFMA GEMM (weights are [out,in] == [N,K] B^T layout)
//  - decoder: weight-stationary persistent DATAFLOW kernel, 213 blocks.
//    Sync: producer-private epoch slots -> watcher block -> per-consumer flag
//    lines (contention-free). Ring slots (emb/h0/h1, 64 KB each, never reused)
//    are staged into LDS via global_load_lds (zero-VGPR async DMA; fixes the
//    consumer load-dribble under 192-VGPR weight pressure), with a per-row
//    16B-block XOR swizzle applied at producer store AND LDS read.
//    Producers store uncached (sc0 sc1); consumers read fresh ring addresses
//    through the normal cache path (per-XCD L2 multicast).
// ---------------------------------------------------------------------------

typedef unsigned short u16;
typedef __attribute__((ext_vector_type(8))) short short8;
typedef __attribute__((ext_vector_type(4))) float f32x4;

#define GELU_FLG 1
#define BF16_FLG 2
#define NBLK 213
#define DEC_STEPS 540

__device__ __forceinline__ u16 f2b(float f){
  union { float f; unsigned u; } c; c.f = f;
  return (u16)((c.u + 0x7fffu + ((c.u >> 16) & 1u)) >> 16);   // RNE
}
__device__ __forceinline__ short8 ld8(const u16* p){
  return *reinterpret_cast<const short8*>(p);
}
__device__ __forceinline__ short8 lds8(const void* p){
  return *reinterpret_cast<const short8*>(p);
}
__device__ __forceinline__ float ldfc(const float* p){
  return __hip_atomic_load(p, __ATOMIC_RELAXED, __HIP_MEMORY_SCOPE_AGENT);
}
__device__ __forceinline__ void stfc(float* p, float v){
  __hip_atomic_store(p, v, __ATOMIC_RELAXED, __HIP_MEMORY_SCOPE_AGENT);
}
__device__ __forceinline__ void stu32c(void* p, unsigned v){
  __hip_atomic_store((unsigned*)p, v, __ATOMIC_RELAXED, __HIP_MEMORY_SCOPE_AGENT);
}
__device__ __forceinline__ void st16c(u16* p, unsigned v){
  asm volatile("global_store_short %0, %1, off sc0 sc1" :: "v"(p), "v"(v) : "memory");
}
__device__ __forceinline__ f32x4 mfma16(short8 a, short8 b, f32x4 c){
  return __builtin_amdgcn_mfma_f32_16x16x32_bf16(a, b, c, 0, 0, 0);
}
__device__ __forceinline__ float gelu_f(float x){
  return 0.5f * x * (1.f + erff(x * 0.70710678118654752f));
}
__device__ __forceinline__ float sigmoid_f(float x){
  return 1.f / (1.f + __expf(-x));
}
__device__ __forceinline__ float tanh_f(float x){
  float e = __expf(-2.f * x);
  return (1.f - e) / (1.f + e);
}

// async-stage KB x 1KB chunks of a ring slot into LDS (wave q takes chunks
// q, q+4, ...). Per-lane global src; wave-uniform LDS dest (+lane*16 by HW).
template<int KB>
__device__ __forceinline__ void stageN(unsigned* ldsbase, const void* gbase, int lane, int q){
  const char* g = (const char*)gbase;
  #pragma unroll
  for (int c = 0; c < KB / 4; ++c){
    int cc = q + c * 4;
    __builtin_amdgcn_global_load_lds((const unsigned*)(g + (size_t)cc * 1024 + lane * 16),
                                     ldsbase + cc * 256, 16, 0, 0);
  }
}

// ---------------- elementwise / gather kernels ----------------

__global__ void f2b_k(const float* __restrict__ s, u16* __restrict__ d, int n){
  int i = blockIdx.x * 256 + threadIdx.x;
  if (i < n) d[i] = f2b(s[i]);
}

__global__ void gather_xc_k(const float* __restrict__ mo, const float* __restrict__ lxm,
                            u16* __restrict__ xc, u16* __restrict__ pre_mo){
  int i = blockIdx.x * 256 + threadIdx.x;
  if (i >= 32 * 384) return;
  int n = i / 384, c = i - n * 384;
  float v = (c < 256) ? mo[(size_t)(n * 256 + c) * 600 + 29]
                      : lxm[(size_t)(n * 128 + (c - 256)) * 20];
  u16 h = f2b(v);
  xc[i] = h;
  if (c < 256) pre_mo[n * 256 + c] = h;
}

__global__ void lxm_g_k(const float* __restrict__ lxm, u16* __restrict__ o){
  int i = blockIdx.x * 256 + threadIdx.x;
  if (i >= 18 * 32 * 128) return;
  int c = i & 127, rest = i >> 7;
  int n = rest & 31, b = rest >> 5;
  o[i] = f2b(lxm[(size_t)(n * 128 + c) * 20 + 1 + b]);
}

__global__ void split_h_k(const float* __restrict__ hraw, u16* __restrict__ h0, u16* __restrict__ h1,
                          float* __restrict__ h0f, float* __restrict__ h1f){
  int i = blockIdx.x * 256 + threadIdx.x;
  if (i >= 32 * 1024) return;
  int n = i >> 10, c = i & 1023;
  float a = hraw[(size_t)n * 2048 + c];
  float b = hraw[(size_t)n * 2048 + 1024 + c];
  h0[i] = f2b(a); h1[i] = f2b(b);
  h0f[i] = a;     h1f[i] = b;
}

__global__ void build_xc0_k(const u16* __restrict__ pre_mo, const u16* __restrict__ aud_seq,
                            const u16* __restrict__ lxm_b, u16* __restrict__ xc0){
  int i = blockIdx.x * 256 + threadIdx.x;
  if (i >= 32 * 640) return;
  int n = i / 640, c = i - n * 640;
  u16 v;
  if (c < 256) v = pre_mo[n * 256 + c];
  else if (c < 512) v = aud_seq[n * 256 + (c - 256)];
  else v = lxm_b[n * 128 + (c - 512)];
  xc0[i] = v;
}

// repack linear [32][1024] bf16 into the swizzled ring-slot layout
__global__ void swz_emb_k(const u16* __restrict__ src, u16* __restrict__ dst){
  int i = blockIdx.x * 256 + threadIdx.x;
  if (i >= 32 * 1024) return;
  int row = i >> 10, col = i & 1023;
  unsigned boff = (unsigned)(row * 2048) + (((unsigned)col * 2) ^ ((row & 7) << 4));
  *(u16*)((char*)dst + boff) = src[i];
}

__global__ void t_wpT_k(const float* __restrict__ wp, u16* __restrict__ wpT){
  int i = blockIdx.x * 256 + threadIdx.x;
  if (i >= 1024 * 256) return;
  int h = i >> 8, j = i & 255;
  wpT[i] = f2b(wp[(size_t)j * 1024 + h]);
}

__global__ void foldW_k(const float* __restrict__ src, const float* __restrict__ g,
                        const float* __restrict__ b, const float* __restrict__ addb,
                        u16* __restrict__ Wg, float* __restrict__ S, float* __restrict__ B, int R){
  int row = blockIdx.x * 4 + (threadIdx.x >> 6);
  if (row >= R) return;
  int lane = threadIdx.x & 63;
  const float* sr = src + (size_t)row * 1024;
  float s = 0.f, bb = 0.f;
  #pragma unroll
  for (int k = 0; k < 16; ++k){
    int c = lane + k * 64;
    float w = sr[c], gw = w * g[c];
    Wg[(size_t)row * 1024 + c] = f2b(gw);
    s += gw; bb += w * b[c];
  }
  #pragma unroll
  for (int m = 1; m < 64; m <<= 1){ s += __shfl_xor(s, m); bb += __shfl_xor(bb, m); }
  if (lane == 0){ S[row] = s; B[row] = bb + (addb ? addb[row] : 0.f); }
}

__global__ void vfold_k(const float* __restrict__ W, int ldw, int off, const float* __restrict__ pb,
                        const float* __restrict__ base, float* __restrict__ v, int R){
  int row = blockIdx.x * 4 + (threadIdx.x >> 6);
  if (row >= R) return;
  int lane = threadIdx.x & 63;
  const float* wr = W + (size_t)row * ldw + off;
  float s = 0.f;
  #pragma unroll
  for (int k = 0; k < 4; ++k){ int j = lane + k * 64; s += wr[j] * pb[j]; }
  #pragma unroll
  for (int m = 1; m < 64; m <<= 1) s += __shfl_xor(s, m);
  if (lane == 0) v[row] = s + (base ? base[row] : 0.f);
}

// ---------------- im2col kernels ----------------

__global__ void im2col0_k(const float* __restrict__ aud, u16* __restrict__ A, int row0, long long tot){
  long long i = (long long)blockIdx.x * 256 + threadIdx.x;
  if (i >= tot) return;
  int k = (int)(i % 896);
  int row = row0 + (int)(i / 896);
  int ci = k / 7, kk = k - ci * 7;
  int p = row % 84, bn = row / 84;
  int b = bn >> 5, n = bn & 31;
  A[i] = f2b(aud[(size_t)(n * 128 + ci) * 600 + b * 30 + p + kk]);
}

__global__ void im2col1_k(const u16* __restrict__ O0, u16* __restrict__ A, int row0, long long tot){
  long long i = (long long)blockIdx.x * 256 + threadIdx.x;
  if (i >= tot) return;
  int k = (int)(i % 1280);
  int row = row0 + (int)(i / 1280);
  int ci = k / 5, kk = k - ci * 5;
  int p = row % 80, bn = row / 80;
  A[i] = O0[(size_t)(bn * 84 + p + kk) * 256 + ci];
}

__global__ void im2col2_k(const u16* __restrict__ O1, u16* __restrict__ A, int row0, long long tot){
  long long i = (long long)blockIdx.x * 256 + threadIdx.x;
  if (i >= tot) return;
  int k = (int)(i & 1023);
  int row = row0 + (int)(i >> 10);
  int ci = k >> 2, kk = k & 3;
  int p = row % 40, bn = row / 40;
  int pos = 2 * p - 1 + kk;
  A[i] = (pos >= 0 && pos < 80) ? O1[(size_t)(bn * 80 + pos) * 256 + ci] : (u16)0;
}

// ---------------- GEMM: C[M,N] = A[M,K] @ W[N,K]^T  (bf16 MFMA) ----------------

__global__ void gemm_bt(const u16* __restrict__ A, int lda,
                        const u16* __restrict__ W, int ldw, const float* __restrict__ bias,
                        void* __restrict__ outp, int M, int N, int K, int flags){
  const int lane = threadIdx.x & 63, widx = threadIdx.x >> 6;
  const int m0 = blockIdx.x * 64 + widx * 16;
  if (m0 >= M) return;
  const int n0 = blockIdx.y * 64;
  const int r = lane & 15, g4 = lane >> 4;
  const u16* arow = A + (size_t)(m0 + r) * lda + g4 * 8;
  const u16* wrow = W + (size_t)(n0 + r) * ldw + g4 * 8;
  f32x4 acc[4];
  const f32x4 FZ = {0.f, 0.f, 0.f, 0.f};
  acc[0] = FZ; acc[1] = FZ; acc[2] = FZ; acc[3] = FZ;
  for (int k = 0; k < K; k += 32){
    short8 a = ld8(arow + k);
    #pragma unroll
    for (int j = 0; j < 4; ++j)
      acc[j] = mfma16(a, ld8(wrow + (size_t)j * 16 * ldw + k), acc[j]);
  }
  #pragma unroll
  for (int j = 0; j < 4; ++j){
    int col = n0 + j * 16 + r;
    float bv = bias ? bias[col] : 0.f;
    #pragma unroll
    for (int q = 0; q < 4; ++q){
      int row = m0 + g4 * 4 + q;
      float v = acc[j][q] + bv;
      if (flags & GELU_FLG) v = gelu_f(v);
      if (flags & BF16_FLG) ((u16*)outp)[(size_t)row * N + col] = f2b(v);
      else                  ((float*)outp)[(size_t)row * N + col] = v;
    }
  }
}

// ---------------- encoder LayerNorm -> aud_seq (bf16) ----------------

__global__ void enc_ln_k(const float* __restrict__ O3, const float* __restrict__ g,
                         const float* __restrict__ bb, u16* __restrict__ aud_seq){
  int rid = blockIdx.x * 4 + (threadIdx.x >> 6);
  int lane = threadIdx.x & 63;
  int b = rid / 960, rem = rid - b * 960;
  int p2 = rem >> 5, n = rem & 31;
  int orow = (b * 32 + n) * 40 + p2;
  const float4 v = *reinterpret_cast<const float4*>(O3 + (size_t)orow * 256 + lane * 4);
  float s  = v.x + v.y + v.z + v.w;
  float s2 = v.x * v.x + v.y * v.y + v.z * v.z + v.w * v.w;
  #pragma unroll
  for (int m = 1; m < 64; m <<= 1){ s += __shfl_xor(s, m); s2 += __shfl_xor(s2, m); }
  float mu = s * (1.f / 256.f);
  float var = s2 * (1.f / 256.f) - mu * mu;
  float rs = rsqrtf(var + 1e-5f);
  int c = lane * 4;
  u16* dst = aud_seq + (size_t)rid * 256 + c;
  dst[0] = f2b((v.x - mu) * rs * g[c + 0] + bb[c + 0]);
  dst[1] = f2b((v.y - mu) * rs * g[c + 1] + bb[c + 1]);
  dst[2] = f2b((v.z - mu) * rs * g[c + 2] + bb[c + 2]);
  dst[3] = f2b((v.w - mu) * rs * g[c + 3] + bb[c + 3]);
}

// ---------------- persistent weight-stationary dataflow decoder ----------------

struct DecArgs {
  const u16 *aud_seq, *lxm_b;
  const u16 *wih0, *whh0, *wih1, *whh1, *wd;
  const u16 *wpg, *Wdpg, *Wgpg;
  const float *Sp, *Bp, *S1, *B1, *S2, *B2, *vX, *vG;
  const float *bih0, *bhh0, *bih1, *bhh1;
  const u16 *h0init, *h1init;
  u16 *embR, *h0R, *h1R;                 // rings: slot t = 32x1024 bf16 (64 KB, SWIZZLED)
  float *statsR;                         // ring:  slot t = [64 blk][64] f32
  float *GxR, *XalR, *GalR;              // mod-8 rings (flag-gated reuse)
  float *h0f, *h1f, *out;
  int *sync;
};

__device__ __forceinline__ void sigslot(int* slot, int ep){
  asm volatile("s_waitcnt vmcnt(0)" ::: "memory");
  __syncthreads();
  if (threadIdx.x == 0)
    __hip_atomic_store(slot, ep, __ATOMIC_RELAXED, __HIP_MEMORY_SCOPE_AGENT);
}
__device__ __forceinline__ void waitflag(const int* flag, int tgt){
  if (threadIdx.x == 0){
    while (__hip_atomic_load(flag, __ATOMIC_RELAXED, __HIP_MEMORY_SCOPE_AGENT) < tgt)
      __builtin_amdgcn_s_sleep(1);
  }
  __syncthreads();
}
__device__ __forceinline__ void stage_fence(){
  asm volatile("s_waitcnt vmcnt(0)" ::: "memory");
  __syncthreads();
}

__global__ __launch_bounds__(256, 1) void decode_k(DecArgs A){
  const int tid = threadIdx.x;
  const int lane = tid & 63, q = tid >> 6;
  const int r = lane & 15, g4 = lane >> 4;
  const int blk = blockIdx.x;
  __shared__ __align__(16) unsigned smw[25088];   // 64KB staging + 34.8KB exch/stats
  char* const stg = (char*)smw;
  float* const exch = (float*)(smw + 16384);      // L0/L1: [4][4][32][17]
  float* const stgStats = (float*)(smw + 16384);  // PE: 16KB stats staging
  const f32x4 FZ = {0.f, 0.f, 0.f, 0.f};
  const int sw = (r & 7) << 4;
  int* const slotH0 = A.sync;
  int* const slotH1 = A.sync + 128 * 16;
  int* const slotPE = A.sync + 256 * 16;
  int* const slotAL = A.sync + 384 * 16;
  int* const flagH0 = A.sync + 512 * 16;
  int* const flagH1 = A.sync + 768 * 16;
  int* const flagPE = A.sync + 1024 * 16;
  int* const flagAL = A.sync + 1280 * 16;

  if (blk < 64){
    // ---------------- L0: h0 producer ----------------
    const int c0 = blk * 16;
    const int kq = q * 256;
    int* const myFpe = flagPE + blk * 16;
    int* const myFh0 = flagH0 + blk * 16;
    int* const mySlot = slotH0 + blk * 16;
    short8 we[24], wh[24];
    #pragma unroll
    for (int g = 0; g < 3; ++g)
      #pragma unroll
      for (int ch = 0; ch < 8; ++ch){
        we[g * 8 + ch] = ld8(A.wih0 + (size_t)(g * 1024 + c0 + r) * 1664 + kq + ch * 32 + g4 * 8);
        wh[g * 8 + ch] = ld8(A.whh0 + (size_t)(g * 1024 + c0 + r) * 1024 + kq + ch * 32 + g4 * 8);
      }
    const int n_c = tid >> 3;
    const int cc0 = (tid & 7) * 2;
    const int colA = c0 + cc0, colB = colA + 1;
    const unsigned stoff = (unsigned)(n_c * 2048) + (((unsigned)colA * 2) ^ ((n_c & 7) << 4));
    const float bi_r[2] = {A.bih0[colA], A.bih0[colB]};
    const float bi_z[2] = {A.bih0[1024 + colA], A.bih0[1024 + colB]};
    const float bi_n[2] = {A.bih0[2048 + colA], A.bih0[2048 + colB]};
    const float bh_r[2] = {A.bhh0[colA], A.bhh0[colB]};
    const float bh_z[2] = {A.bhh0[1024 + colA], A.bhh0[1024 + colB]};
    const float bh_n[2] = {A.bhh0[2048 + colA], A.bhh0[2048 + colB]};
    f32x4 ar[2], az[2], ani[2], anh[2];
    ar[0] = FZ; ar[1] = FZ; az[0] = FZ; az[1] = FZ; ani[0] = FZ; ani[1] = FZ; anh[0] = FZ; anh[1] = FZ;
    #pragma unroll
    for (int ch = 0; ch < 8; ++ch){
      short8 a0 = ld8(A.h0init + r * 1024 + kq + ch * 32 + g4 * 8);
      short8 a1 = ld8(A.h0init + (16 + r) * 1024 + kq + ch * 32 + g4 * 8);
      ar[0] = mfma16(a0, wh[ch], ar[0]);        ar[1] = mfma16(a1, wh[ch], ar[1]);
      az[0] = mfma16(a0, wh[8 + ch], az[0]);    az[1] = mfma16(a1, wh[8 + ch], az[1]);
      anh[0] = mfma16(a0, wh[16 + ch], anh[0]); anh[1] = mfma16(a1, wh[16 + ch], anh[1]);
    }
    #pragma unroll 1
    for (int t = 0; t < DEC_STEPS; ++t){
      if (t > 0) waitflag(myFpe, t);
      const u16*  embT = A.embR + (size_t)t * 32768;
      u16*        h0T  = A.h0R  + (size_t)t * 32768;
      const float* GxT = A.GxR + (size_t)(t & 7) * 98304;
      stageN<64>(smw, embT, lane, q);
      float pgr[2], pgz[2], pgn[2], phf[2];
      #pragma unroll
      for (int e = 0; e < 2; ++e){
        int col = c0 + cc0 + e;
        pgr[e] = ldfc(GxT + n_c * 3072 + col);
        pgz[e] = ldfc(GxT + n_c * 3072 + 1024 + col);
        pgn[e] = ldfc(GxT + n_c * 3072 + 2048 + col);
        phf[e] = A.h0f[n_c * 1024 + col];
      }
      stage_fence();
      #pragma unroll
      for (int ch = 0; ch < 8; ++ch){
        int off = ((kq + ch * 32 + g4 * 8) * 2) ^ sw;
        short8 a0 = lds8(stg + r * 2048 + off);
        short8 a1 = lds8(stg + (16 + r) * 2048 + off);
        ar[0] = mfma16(a0, we[ch], ar[0]);        ar[1] = mfma16(a1, we[ch], ar[1]);
        az[0] = mfma16(a0, we[8 + ch], az[0]);    az[1] = mfma16(a1, we[8 + ch], az[1]);
        ani[0] = mfma16(a0, we[16 + ch], ani[0]); ani[1] = mfma16(a1, we[16 + ch], ani[1]);
      }
      #pragma unroll
      for (int m = 0; m < 2; ++m)
        #pragma unroll
        for (int j = 0; j < 4; ++j){
          int row = m * 16 + g4 * 4 + j;
          exch[((q * 4 + 0) * 32 + row) * 17 + r] = ar[m][j];
          exch[((q * 4 + 1) * 32 + row) * 17 + r] = az[m][j];
          exch[((q * 4 + 2) * 32 + row) * 17 + r] = ani[m][j];
          exch[((q * 4 + 3) * 32 + row) * 17 + r] = anh[m][j];
        }
      __syncthreads();
      float hv2[2];
      #pragma unroll
      for (int e = 0; e < 2; ++e){
        int cc = cc0 + e, col = c0 + cc;
        float sr = bi_r[e] + bh_r[e] + pgr[e];
        float sz = bi_z[e] + bh_z[e] + pgz[e];
        float si = bi_n[e] + pgn[e];
        float sh = bh_n[e];
        #pragma unroll
        for (int qq = 0; qq < 4; ++qq){
          sr += exch[((qq * 4 + 0) * 32 + n_c) * 17 + cc];
          sz += exch[((qq * 4 + 1) * 32 + n_c) * 17 + cc];
          si += exch[((qq * 4 + 2) * 32 + n_c) * 17 + cc];
          sh += exch[((qq * 4 + 3) * 32 + n_c) * 17 + cc];
        }
        float rg = sigmoid_f(sr), zg = sigmoid_f(sz);
        float ng = tanh_f(si + rg * sh);
        float hv = (1.f - zg) * ng + zg * phf[e];
        A.h0f[n_c * 1024 + col] = hv;
        hv2[e] = hv;
      }
      stu32c((char*)h0T + stoff,
             (unsigned)f2b(hv2[0]) | ((unsigned)f2b(hv2[1]) << 16));
      __syncthreads();
      sigslot(mySlot, t + 1);
      waitflag(myFh0, t + 1);
      stageN<64>(smw, h0T, lane, q);
      stage_fence();
      ar[0] = FZ; ar[1] = FZ; az[0] = FZ; az[1] = FZ; ani[0] = FZ; ani[1] = FZ; anh[0] = FZ; anh[1] = FZ;
      #pragma unroll
      for (int ch = 0; ch < 8; ++ch){
        int off = ((kq + ch * 32 + g4 * 8) * 2) ^ sw;
        short8 a0 = lds8(stg + r * 2048 + off);
        short8 a1 = lds8(stg + (16 + r) * 2048 + off);
        ar[0] = mfma16(a0, wh[ch], ar[0]);        ar[1] = mfma16(a1, wh[ch], ar[1]);
        az[0] = mfma16(a0, wh[8 + ch], az[0]);    az[1] = mfma16(a1, wh[8 + ch], az[1]);
        anh[0] = mfma16(a0, wh[16 + ch], anh[0]); anh[1] = mfma16(a1, wh[16 + ch], anh[1]);
      }
    }
  } else if (blk < 128){
    // ---------------- L1: h1 producer ----------------
    const int c0 = (blk - 64) * 16;
    const int kq = q * 256;
    int* const myFh0 = flagH0 + blk * 16;
    int* const myFh1 = flagH1 + blk * 16;
    int* const mySlot = slotH1 + (blk - 64) * 16;
    short8 wi[24], wh[24];
    #pragma unroll
    for (int g = 0; g < 3; ++g)
      #pragma unroll
      for (int ch = 0; ch < 8; ++ch){
        wi[g * 8 + ch] = ld8(A.wih1 + (size_t)(g * 1024 + c0 + r) * 1024 + kq + ch * 32 + g4 * 8);
        wh[g * 8 + ch] = ld8(A.whh1 + (size_t)(g * 1024 + c0 + r) * 1024 + kq + ch * 32 + g4 * 8);
      }
    const int n_c = tid >> 3;
    const int cc0 = (tid & 7) * 2;
    const int colA = c0 + cc0, colB = colA + 1;
    const unsigned stoff = (unsigned)(n_c * 2048) + (((unsigned)colA * 2) ^ ((n_c & 7) << 4));
    const float bi_r[2] = {A.bih1[colA], A.bih1[colB]};
    const float bi_z[2] = {A.bih1[1024 + colA], A.bih1[1024 + colB]};
    const float bi_n[2] = {A.bih1[2048 + colA], A.bih1[2048 + colB]};
    const float bh_r[2] = {A.bhh1[colA], A.bhh1[colB]};
    const float bh_z[2] = {A.bhh1[1024 + colA], A.bhh1[1024 + colB]};
    const float bh_n[2] = {A.bhh1[2048 + colA], A.bhh1[2048 + colB]};
    f32x4 ar[2], az[2], ani[2], anh[2];
    ar[0] = FZ; ar[1] = FZ; az[0] = FZ; az[1] = FZ; ani[0] = FZ; ani[1] = FZ; anh[0] = FZ; anh[1] = FZ;
    #pragma unroll
    for (int ch = 0; ch < 8; ++ch){
      short8 a0 = ld8(A.h1init + r * 1024 + kq + ch * 32 + g4 * 8);
      short8 a1 = ld8(A.h1init + (16 + r) * 1024 + kq + ch * 32 + g4 * 8);
      ar[0] = mfma16(a0, wh[ch], ar[0]);        ar[1] = mfma16(a1, wh[ch], ar[1]);
      az[0] = mfma16(a0, wh[8 + ch], az[0]);    az[1] = mfma16(a1, wh[8 + ch], az[1]);
      anh[0] = mfma16(a0, wh[16 + ch], anh[0]); anh[1] = mfma16(a1, wh[16 + ch], anh[1]);
    }
    #pragma unroll 1
    for (int t = 0; t < DEC_STEPS; ++t){
      waitflag(myFh0, t + 1);
      const u16* h0T = A.h0R + (size_t)t * 32768;
      u16*       h1T = A.h1R + (size_t)t * 32768;
      stageN<64>(smw, h0T, lane, q);
      float phf[2];
      phf[0] = A.h1f[n_c * 1024 + colA];
      phf[1] = A.h1f[n_c * 1024 + colB];
      stage_fence();
      #pragma unroll
      for (int ch = 0; ch < 8; ++ch){
        int off = ((kq + ch * 32 + g4 * 8) * 2) ^ sw;
        short8 a0 = lds8(stg + r * 2048 + off);
        short8 a1 = lds8(stg + (16 + r) * 2048 + off);
        ar[0] = mfma16(a0, wi[ch], ar[0]);        ar[1] = mfma16(a1, wi[ch], ar[1]);
        az[0] = mfma16(a0, wi[8 + ch], az[0]);    az[1] = mfma16(a1, wi[8 + ch], az[1]);
        ani[0] = mfma16(a0, wi[16 + ch], ani[0]); ani[1] = mfma16(a1, wi[16 + ch], ani[1]);
      }
      #pragma unroll
      for (int m = 0; m < 2; ++m)
        #pragma unroll
        for (int j = 0; j < 4; ++j){
          int row = m * 16 + g4 * 4 + j;
          exch[((q * 4 + 0) * 32 + row) * 17 + r] = ar[m][j];
          exch[((q * 4 + 1) * 32 + row) * 17 + r] = az[m][j];
          exch[((q * 4 + 2) * 32 + row) * 17 + r] = ani[m][j];
          exch[((q * 4 + 3) * 32 + row) * 17 + r] = anh[m][j];
        }
      __syncthreads();
      float hv2[2];
      #pragma unroll
      for (int e = 0; e < 2; ++e){
        int cc = cc0 + e, col = c0 + cc;
        float sr = bi_r[e] + bh_r[e];
        float sz = bi_z[e] + bh_z[e];
        float si = bi_n[e];
        float sh = bh_n[e];
        #pragma unroll
        for (int qq = 0; qq < 4; ++qq){
          sr += exch[((qq * 4 + 0) * 32 + n_c) * 17 + cc];
          sz += exch[((qq * 4 + 1) * 32 + n_c) * 17 + cc];
          si += exch[((qq * 4 + 2) * 32 + n_c) * 17 + cc];
          sh += exch[((qq * 4 + 3) * 32 + n_c) * 17 + cc];
        }
        float rg = sigmoid_f(sr), zg = sigmoid_f(sz);
        float ng = tanh_f(si + rg * sh);
        float hv = (1.f - zg) * ng + zg * phf[e];
        A.h1f[n_c * 1024 + col] = hv;
        hv2[e] = hv;
      }
      stu32c((char*)h1T + stoff,
             (unsigned)f2b(hv2[0]) | ((unsigned)f2b(hv2[1]) << 16));
      float sv = hv2[0] + hv2[1], sq = hv2[0] * hv2[0] + hv2[1] * hv2[1];
      sv += __shfl_xor(sv, 1); sq += __shfl_xor(sq, 1);
      sv += __shfl_xor(sv, 2); sq += __shfl_xor(sq, 2);
      sv += __shfl_xor(sv, 4); sq += __shfl_xor(sq, 4);
      if ((tid & 7) == 0){
        stfc(A.statsR + (size_t)t * 4096 + (blk - 64) * 64 + n_c, sv);
        stfc(A.statsR + (size_t)t * 4096 + (blk - 64) * 64 + 32 + n_c, sq);
      }
      __syncthreads();
      sigslot(mySlot, t + 1);
      waitflag(myFh1, t + 1);
      stageN<64>(smw, h1T, lane, q);
      stage_fence();
      ar[0] = FZ; ar[1] = FZ; az[0] = FZ; az[1] = FZ; ani[0] = FZ; ani[1] = FZ; anh[0] = FZ; anh[1] = FZ;
      #pragma unroll
      for (int ch = 0; ch < 8; ++ch){
        int off = ((kq + ch * 32 + g4 * 8) * 2) ^ sw;
        short8 a0 = lds8(stg + r * 2048 + off);
        short8 a1 = lds8(stg + (16 + r) * 2048 + off);
        ar[0] = mfma16(a0, wh[ch], ar[0]);        ar[1] = mfma16(a1, wh[ch], ar[1]);
        az[0] = mfma16(a0, wh[8 + ch], az[0]);    az[1] = mfma16(a1, wh[8 + ch], az[1]);
        anh[0] = mfma16(a0, wh[16 + ch], anh[0]); anh[1] = mfma16(a1, wh[16 + ch], anh[1]);
      }
    }
  } else if (blk < 196){
    // ---------------- PE: pred / emb_{t+1} / Gx_{t+1} ----------------
    const int tile = (blk - 128) * 4 + q;
    int* const myFh1 = flagH1 + blk * 16;
    int* const myFal = flagAL + blk * 16;
    int* const mySlot = slotPE + (blk - 128) * 16;
    int jt, c0;
    const u16* wsrc; const float *Sv, *Bv;
    if (tile < 16)      { jt = 0; c0 = tile * 16;        wsrc = A.wpg;  Sv = A.Sp; Bv = A.Bp; }
    else if (tile < 80) { jt = 1; c0 = (tile - 16) * 16; wsrc = A.Wdpg; Sv = A.S1; Bv = A.B1; }
    else                { jt = 2; c0 = (tile - 80) * 16; wsrc = A.Wgpg; Sv = A.S2; Bv = A.B2; }
    short8 w[32];
    #pragma unroll
    for (int ch = 0; ch < 32; ++ch)
      w[ch] = ld8(wsrc + (size_t)(c0 + r) * 1024 + ch * 32 + g4 * 8);
    const float Sc = Sv[c0 + r], Bc = Bv[c0 + r];
    const int col = c0 + r;
    #pragma unroll 1
    for (int t = 0; t < DEC_STEPS; ++t){
      waitflag(myFh1, t + 1);
      waitflag(myFal, t + 1);
      const u16*   h1T = A.h1R + (size_t)t * 32768;
      const float* stT = A.statsR + (size_t)t * 4096;
      const int sl = (t + 1) & 7;
      stageN<64>(smw, h1T, lane, q);
      stageN<16>(smw + 16384, stT, lane, q);
      const float* XalT = A.XalR + (size_t)sl * 32768;
      const float* GalT = A.GalR + (size_t)sl * 98304;
      float addv[2][4];
      #pragma unroll
      for (int m = 0; m < 2; ++m)
        #pragma unroll
        for (int j = 0; j < 4; ++j){
          int n = m * 16 + g4 * 4 + j;
          addv[m][j] = (jt == 1) ? ldfc(XalT + n * 1024 + col)
                     : (jt == 2) ? ldfc(GalT + n * 3072 + col) : 0.f;
        }
      stage_fence();
      float sacc = 0.f;
      #pragma unroll
      for (int b2 = 0; b2 < 64; ++b2) sacc += stgStats[b2 * 64 + lane];
      float muA[2][4], rsA[2][4];
      #pragma unroll
      for (int m = 0; m < 2; ++m)
        #pragma unroll
        for (int j = 0; j < 4; ++j){
          int n = m * 16 + g4 * 4 + j;
          float sv = __shfl(sacc, n), sq = __shfl(sacc, 32 + n);
          float mu = sv * (1.f / 1024.f);
          muA[m][j] = mu;
          rsA[m][j] = rsqrtf(sq * (1.f / 1024.f) - mu * mu + 1e-5f);
        }
      f32x4 a0 = FZ, a1 = FZ;
      #pragma unroll
      for (int ch = 0; ch < 32; ++ch){
        int off = ((ch * 32 + g4 * 8) * 2) ^ sw;
        short8 x0 = lds8(stg + r * 2048 + off);
        short8 x1 = lds8(stg + (16 + r) * 2048 + off);
        a0 = mfma16(x0, w[ch], a0);
        a1 = mfma16(x1, w[ch], a1);
      }
      u16*   embN = A.embR + (size_t)(t + 1) * 32768;
      float* GxN  = A.GxR + (size_t)sl * 98304;
      #pragma unroll
      for (int m = 0; m < 2; ++m)
        #pragma unroll
        for (int j = 0; j < 4; ++j){
          int n = m * 16 + g4 * 4 + j;
          float acc = (m ? a1[j] : a0[j]);
          float v = rsA[m][j] * (acc - muA[m][j] * Sc) + Bc;
          if (jt == 0){
            A.out[(size_t)n * (256 * 540) + (size_t)col * 540 + t] = v;
          } else if (jt == 1){
            float pre = v + addv[m][j];
            unsigned boff = (unsigned)(n * 2048) + (((unsigned)col * 2) ^ ((n & 7) << 4));
            st16c((u16*)((char*)embN + boff), (unsigned)f2b(gelu_f(pre)));
          } else {
            stfc(GxN + n * 3072 + col, v + addv[m][j]);
          }
        }
      sigslot(mySlot, t + 1);
    }
  } else if (blk < 212){
    // ---------------- AL: audio/lxm partials for step t+1 ----------------
    const int wg = (blk - 196) * 4 + q;
    int* const myFpe = flagPE + blk * 16;
    int* const mySlot = slotAL + (blk - 196) * 16;
    const int at0 = wg * 4;
    short8 w[48];
    float vb[4];
    #pragma unroll
    for (int j = 0; j < 4; ++j){
      int at = at0 + j;
      if (at < 64){
        #pragma unroll
        for (int ch = 0; ch < 12; ++ch)
          w[j * 12 + ch] = ld8(A.wd + (size_t)(at * 16 + r) * 640 + 256 + ch * 32 + g4 * 8);
        vb[j] = A.vX[at * 16 + r];
      } else {
        #pragma unroll
        for (int ch = 0; ch < 12; ++ch)
          w[j * 12 + ch] = ld8(A.wih0 + (size_t)((at - 64) * 16 + r) * 1664 + 1280 + ch * 32 + g4 * 8);
        vb[j] = A.vG[(at - 64) * 16 + r];
      }
    }
    #pragma unroll 1
    for (int t = 0; t < DEC_STEPS; ++t){
      if (t >= 8) waitflag(myFpe, t - 7);
      const int tn = t + 1;
      const int tread = (tn > 539) ? 539 : tn;
      const int bn = tread / 30;
      const int sl = tn & 7;
      float* XalW = A.XalR + (size_t)sl * 32768;
      float* GalW = A.GalR + (size_t)sl * 98304;
      short8 af0[12], af1[12];
      #pragma unroll
      for (int ch = 0; ch < 12; ++ch){
        int kk = ch * 32 + g4 * 8;
        if (ch < 8){
          af0[ch] = ld8(A.aud_seq + ((size_t)tread * 32 + r) * 256 + kk);
          af1[ch] = ld8(A.aud_seq + ((size_t)tread * 32 + 16 + r) * 256 + kk);
        } else {
          af0[ch] = ld8(A.lxm_b + ((size_t)bn * 32 + r) * 128 + kk - 256);
          af1[ch] = ld8(A.lxm_b + ((size_t)bn * 32 + 16 + r) * 128 + kk - 256);
        }
      }
      #pragma unroll
      for (int j = 0; j < 4; ++j){
        f32x4 c0a = FZ, c1a = FZ;
        #pragma unroll
        for (int ch = 0; ch < 12; ++ch){
          c0a = mfma16(af0[ch], w[j * 12 + ch], c0a);
          c1a = mfma16(af1[ch], w[j * 12 + ch], c1a);
        }
        int at = at0 + j;
        #pragma unroll
        for (int m = 0; m < 2; ++m)
          #pragma unroll
          for (int jj = 0; jj < 4; ++jj){
            int n = m * 16 + g4 * 4 + jj;
            float v = (m ? c1a[jj] : c0a[jj]) + vb[j];
            if (at < 64) stfc(XalW + n * 1024 + at * 16 + r, v);
            else         stfc(GalW + n * 3072 + (at - 64) * 16 + r, v);
          }
      }
      sigslot(mySlot, tn);
    }
  } else {
    // ---------------- watcher block: one wave per group ----------------
    const int NPs[4] = {64, 64, 68, 16};
    const int NP = NPs[q];
    int* const slotG = A.sync + q * 128 * 16;
    int* const flagG = A.sync + (512 + q * 256) * 16;
    const int idx1 = (lane < NP) ? lane : 0;
    const int extra = NP - 64;
    #pragma unroll 1
    for (int t = 1; t <= DEC_STEPS; ++t){
      for (;;){
        int v = __hip_atomic_load(slotG + idx1 * 16, __ATOMIC_RELAXED, __HIP_MEMORY_SCOPE_AGENT);
        bool ok = (v >= t);
        if (extra > 0 && lane < extra){
          int v2 = __hip_atomic_load(slotG + (64 + lane) * 16, __ATOMIC_RELAXED, __HIP_MEMORY_SCOPE_AGENT);
          ok = ok && (v2 >= t);
        }
        if (__all(ok)) break;
        __builtin_amdgcn_s_sleep(1);
      }
      #pragma unroll 1
      for (int c = lane; c < NBLK; c += 64)
        __hip_atomic_store(flagG + c * 16, t, __ATOMIC_RELAXED, __HIP_MEMORY_SCOPE_AGENT);
    }
  }
}

// ---------------------------------------------------------------------------

extern "C" void kernel_launch(void* const* d_in, const int* in_sizes, int n_in,
                              void* d_out, int out_size, void* d_ws, size_t ws_size,
                              hipStream_t stream) {
  enum { I_AUD=0, I_MO=1, I_LXM=2, I_AEW0=3, I_AEB0=4, I_AEW1=5, I_AEB1=6, I_AEW2=7, I_AEB2=8,
         I_AEW3=9, I_AEB3=10, I_AELNG=11, I_AELNB=12, I_CIW0=13, I_CIB0=14, I_CIW1=15, I_CIB1=16,
         I_CIW2=17, I_CIB2=18, I_DECW=19, I_DECB=20, I_WIH0=21, I_WHH0=22, I_BIH0=23, I_BHH0=24,
         I_WIH1=25, I_WHH1=26, I_BIH1=27, I_BHH1=28, I_LNG=29, I_LNB=30, I_PREDW=31, I_PREDB=32 };

  char* base = (char*)d_ws;
  size_t off = 0;
  auto alloc = [&](size_t bytes)->void*{
    void* p = base + off;
    off += (bytes + 255) & ~(size_t)255;
    return p;
  };

  u16* wd_b   = (u16*)alloc((size_t)1024*640*2);
  u16* wih0_b = (u16*)alloc((size_t)3072*1664*2);
  u16* whh0_b = (u16*)alloc((size_t)3072*1024*2);
  u16* wih1_b = (u16*)alloc((size_t)3072*1024*2);
  u16* whh1_b = (u16*)alloc((size_t)3072*1024*2);
  u16* wc0    = (u16*)alloc((size_t)1024*384*2);
  u16* wc1    = (u16*)alloc((size_t)1024*1024*2);
  u16* wc2    = (u16*)alloc((size_t)2048*1024*2);
  u16* w0k    = (u16*)alloc((size_t)256*896*2);
  u16* w1k    = (u16*)alloc((size_t)256*1280*2);
  u16* w2k    = (u16*)alloc((size_t)256*1024*2);
  u16* w3k    = (u16*)alloc((size_t)256*256*2);
  u16* wpT    = (u16*)alloc((size_t)1024*256*2);
  u16* wpg    = (u16*)alloc((size_t)256*1024*2);
  u16* Wdpg   = (u16*)alloc((size_t)1024*1024*2);
  u16* Wgpg   = (u16*)alloc((size_t)3072*1024*2);
  float* Sp = (float*)alloc(256*4);   float* Bp = (float*)alloc(256*4);
  float* S1 = (float*)alloc(1024*4);  float* B1 = (float*)alloc(1024*4);
  float* S2 = (float*)alloc(3072*4);  float* B2 = (float*)alloc(3072*4);
  float* vX = (float*)alloc(1024*4);  float* vG = (float*)alloc(3072*4);
  u16* aud_seq = (u16*)alloc((size_t)540*32*256*2);
  u16* lxm_b   = (u16*)alloc((size_t)18*32*128*2);
  u16* xc      = (u16*)alloc((size_t)32*384*2);
  u16* xc0     = (u16*)alloc((size_t)32*640*2);
  u16* ci1     = (u16*)alloc((size_t)32*1024*2);
  u16* ci2     = (u16*)alloc((size_t)32*1024*2);
  float* hraw  = (float*)alloc((size_t)32*2048*4);
  u16* h0i     = (u16*)alloc((size_t)32*1024*2);
  u16* h1i     = (u16*)alloc((size_t)32*1024*2);
  float* h0f   = (float*)alloc((size_t)32*1024*4);
  float* h1f   = (float*)alloc((size_t)32*1024*4);
  u16* pre_mo  = (u16*)alloc((size_t)32*256*2);
  u16* emb0    = (u16*)alloc((size_t)32*1024*2);
  float* GxR   = (float*)alloc((size_t)8*32*3072*4);
  float* XalR  = (float*)alloc((size_t)8*32*1024*4);
  float* GalR  = (float*)alloc((size_t)8*32*3072*4);
  int* syncb   = (int*)alloc((size_t)1536*16*4);
  char* enc_base = base + off;
  u16* O0   = (u16*)alloc((size_t)48384*256*2);
  u16* O1   = (u16*)alloc((size_t)46080*256*2);
  u16* O2   = (u16*)alloc((size_t)23040*256*2);
  float* O3 = (float*)alloc((size_t)23040*256*4);
  u16* Abuf = (u16*)alloc((size_t)23040*1280*2);
  float* Wdp_f = (float*)Abuf;
  float* Wgp_f = (float*)((char*)Abuf + (size_t)1024*1024*4 + 256);
  u16* embR     = (u16*)enc_base;
  u16* h0R      = embR + (size_t)541*32768;
  u16* h1R      = h0R + (size_t)540*32768;
  float* statsR = (float*)(h1R + (size_t)540*32768);
  (void)ws_size; (void)in_sizes; (void)n_in; (void)out_size;

  const float* aud = (const float*)d_in[I_AUD];
  const float* mo  = (const float*)d_in[I_MO];
  const float* lxm = (const float*)d_in[I_LXM];
  float* out = (float*)d_out;

  auto cdiv = [](long long a, long long b)->int{ return (int)((a + b - 1) / b); };
  auto cvt = [&](int idx, u16* dst, int n){
    f2b_k<<<cdiv(n,256), 256, 0, stream>>>((const float*)d_in[idx], dst, n);
  };

  cvt(I_DECW, wd_b,   1024*640);
  cvt(I_WIH0, wih0_b, 3072*1664);
  cvt(I_WHH0, whh0_b, 3072*1024);
  cvt(I_WIH1, wih1_b, 3072*1024);
  cvt(I_WHH1, whh1_b, 3072*1024);
  cvt(I_CIW0, wc0,    1024*384);
  cvt(I_CIW1, wc1,    1024*1024);
  cvt(I_CIW2, wc2,    2048*1024);
  cvt(I_AEW0, w0k,    256*896);
  cvt(I_AEW1, w1k,    256*1280);
  cvt(I_AEW2, w2k,    256*1024);
  cvt(I_AEW3, w3k,    256*256);

  for (int c = 0; c < 2; ++c){
    int row0 = c * 24192;
    long long tot = (long long)24192 * 896;
    im2col0_k<<<cdiv(tot,256), 256, 0, stream>>>(aud, Abuf, row0, tot);
    gemm_bt<<<dim3(24192/64, 4), 256, 0, stream>>>(Abuf, 896, w0k, 896, (const float*)d_in[I_AEB0],
        O0 + (size_t)row0*256, 24192, 256, 896, GELU_FLG|BF16_FLG);
  }
  for (int c = 0; c < 2; ++c){
    int row0 = c * 23040;
    long long tot = (long long)23040 * 1280;
    im2col1_k<<<cdiv(tot,256), 256, 0, stream>>>(O0, Abuf, row0, tot);
    gemm_bt<<<dim3(23040/64, 4), 256, 0, stream>>>(Abuf, 1280, w1k, 1280, (const float*)d_in[I_AEB1],
        O1 + (size_t)row0*256, 23040, 256, 1280, GELU_FLG|BF16_FLG);
  }
  {
    long long tot = (long long)23040 * 1024;
    im2col2_k<<<cdiv(tot,256), 256, 0, stream>>>(O1, Abuf, 0, tot);
    gemm_bt<<<dim3(23040/64, 4), 256, 0, stream>>>(Abuf, 1024, w2k, 1024, (const float*)d_in[I_AEB2],
        O2, 23040, 256, 1024, GELU_FLG|BF16_FLG);
  }
  gemm_bt<<<dim3(23040/64, 4), 256, 0, stream>>>(O2, 256, w3k, 256, (const float*)d_in[I_AEB3],
      O3, 23040, 256, 256, GELU_FLG);
  enc_ln_k<<<4320, 256, 0, stream>>>(O3, (const float*)d_in[I_AELNG], (const float*)d_in[I_AELNB], aud_seq);

  lxm_g_k<<<cdiv(18*32*128,256), 256, 0, stream>>>(lxm, lxm_b);
  gather_xc_k<<<cdiv(32*384,256), 256, 0, stream>>>(mo, lxm, xc, pre_mo);
  gemm_bt<<<dim3(1,16), 256, 0, stream>>>(xc, 384, wc0, 384, (const float*)d_in[I_CIB0],
      ci1, 32, 1024, 384, GELU_FLG|BF16_FLG);
  gemm_bt<<<dim3(1,16), 256, 0, stream>>>(ci1, 1024, wc1, 1024, (const float*)d_in[I_CIB1],
      ci2, 32, 1024, 1024, GELU_FLG|BF16_FLG);
  gemm_bt<<<dim3(1,32), 256, 0, stream>>>(ci2, 1024, wc2, 1024, (const float*)d_in[I_CIB2],
      hraw, 32, 2048, 1024, 0);
  split_h_k<<<cdiv(32*1024,256), 256, 0, stream>>>(hraw, h0i, h1i, h0f, h1f);

  t_wpT_k<<<cdiv(1024*256,256), 256, 0, stream>>>((const float*)d_in[I_PREDW], wpT);
  gemm_bt<<<dim3(16,16), 256, 0, stream>>>(wd_b, 640, wpT, 256, nullptr, Wdp_f, 1024, 1024, 256, 0);
  gemm_bt<<<dim3(48,16), 256, 0, stream>>>(wih0_b + 1024, 1664, wpT, 256, nullptr, Wgp_f, 3072, 1024, 256, 0);
  foldW_k<<<cdiv(1024,4), 256, 0, stream>>>(Wdp_f, (const float*)d_in[I_LNG], (const float*)d_in[I_LNB],
      nullptr, Wdpg, S1, B1, 1024);
  foldW_k<<<cdiv(3072,4), 256, 0, stream>>>(Wgp_f, (const float*)d_in[I_LNG], (const float*)d_in[I_LNB],
      nullptr, Wgpg, S2, B2, 3072);
  foldW_k<<<cdiv(256,4), 256, 0, stream>>>((const float*)d_in[I_PREDW], (const float*)d_in[I_LNG],
      (const float*)d_in[I_LNB], (const float*)d_in[I_PREDB], wpg, Sp, Bp, 256);
  vfold_k<<<cdiv(1024,4), 256, 0, stream>>>((const float*)d_in[I_DECW], 640, 0,
      (const float*)d_in[I_PREDB], (const float*)d_in[I_DECB], vX, 1024);
  vfold_k<<<cdiv(3072,4), 256, 0, stream>>>((const float*)d_in[I_WIH0], 1664, 1024,
      (const float*)d_in[I_PREDB], nullptr, vG, 3072);

  build_xc0_k<<<cdiv(32*640,256), 256, 0, stream>>>(pre_mo, aud_seq, lxm_b, xc0);
  gemm_bt<<<dim3(1,16), 256, 0, stream>>>(xc0, 640, wd_b, 640, (const float*)d_in[I_DECB],
      emb0, 32, 1024, 640, GELU_FLG|BF16_FLG);
  swz_emb_k<<<cdiv(32*1024,256), 256, 0, stream>>>(emb0, embR);
  gemm_bt<<<dim3(1,48), 256, 0, stream>>>(xc0, 640, wih0_b + 1024, 1664, nullptr,
      GxR, 32, 3072, 640, 0);

  hipMemsetAsync(syncb, 0, (size_t)1536*16*4, stream);

  DecArgs da;
  da.aud_seq = aud_seq; da.lxm_b = lxm_b;
  da.wih0 = wih0_b; da.whh0 = whh0_b; da.wih1 = wih1_b; da.whh1 = whh1_b; da.wd = wd_b;
  da.wpg = wpg; da.Wdpg = Wdpg; da.Wgpg = Wgpg;
  da.Sp = Sp; da.Bp = Bp; da.S1 = S1; da.B1 = B1; da.S2 = S2; da.B2 = B2; da.vX = vX; da.vG = vG;
  da.bih0 = (const float*)d_in[I_BIH0]; da.bhh0 = (const float*)d_in[I_BHH0];
  da.bih1 = (const float*)d_in[I_BIH1]; da.bhh1 = (const float*)d_in[I_BHH1];
  da.h0init = h0i; da.h1init = h1i;
  da.embR = embR; da.h0R = h0R; da.h1R = h1R; da.statsR = statsR;
  da.GxR = GxR; da.XalR = XalR; da.GalR = GalR;
  da.h0f = h0f; da.h1f = h1f;
  da.out = out; da.sync = syncb;
  decode_k<<<dim3(NBLK), dim3(256), 0, stream>>>(da);
}

// Round 10
// 8078.374 us; speedup vs baseline: 3.0298x; 1.0750x over previous
//
#include <hip/hip_runtime.h>

// ---------------------------------------------------------------------------
// MotionGenerator RNN for MI355X (gfx950).
//  - encoder: im2col + bf16 MFMA GEMM (weights are [out,in] == [N,K] B^T layout)
//  - decoder: weight-stationary persistent DATAFLOW kernel, 212 blocks.
//    Sync: producer-private epoch slots polled DIRECTLY by each consumer's
//    wave 0 (lane i <-> slot i, __all) -- no watcher, no RMW, 1 LLC leg.
//    Ring slots (emb/h0/h1, 64 KB each, never reused) are staged into LDS via
//    global_load_lds (zero-VGPR async DMA), with a per-row 16B-block XOR
//    swizzle applied at producer store AND LDS read. Producers store uncached
//    (sc0 sc1); consumers read fresh ring addresses CACHED (L2 multicast).
// ---------------------------------------------------------------------------

typedef unsigned short u16;
typedef __attribute__((ext_vector_type(8))) short short8;
typedef __attribute__((ext_vector_type(4))) float f32x4;

#define GELU_FLG 1
#define BF16_FLG 2
#define NBLK 212
#define DEC_STEPS 540

__device__ __forceinline__ u16 f2b(float f){
  union { float f; unsigned u; } c; c.f = f;
  return (u16)((c.u + 0x7fffu + ((c.u >> 16) & 1u)) >> 16);   // RNE
}
__device__ __forceinline__ short8 ld8(const u16* p){
  return *reinterpret_cast<const short8*>(p);
}
__device__ __forceinline__ short8 lds8(const void* p){
  return *reinterpret_cast<const short8*>(p);
}
__device__ __forceinline__ float ldfc(const float* p){
  return __hip_atomic_load(p, __ATOMIC_RELAXED, __HIP_MEMORY_SCOPE_AGENT);
}
__device__ __forceinline__ void stfc(float* p, float v){
  __hip_atomic_store(p, v, __ATOMIC_RELAXED, __HIP_MEMORY_SCOPE_AGENT);
}
__device__ __forceinline__ void stu32c(void* p, unsigned v){
  __hip_atomic_store((unsigned*)p, v, __ATOMIC_RELAXED, __HIP_MEMORY_SCOPE_AGENT);
}
__device__ __forceinline__ void st16c(u16* p, unsigned v){
  asm volatile("global_store_short %0, %1, off sc0 sc1" :: "v"(p), "v"(v) : "memory");
}
__device__ __forceinline__ f32x4 mfma16(short8 a, short8 b, f32x4 c){
  return __builtin_amdgcn_mfma_f32_16x16x32_bf16(a, b, c, 0, 0, 0);
}
__device__ __forceinline__ float gelu_f(float x){
  return 0.5f * x * (1.f + erff(x * 0.70710678118654752f));
}
__device__ __forceinline__ float sigmoid_f(float x){
  return 1.f / (1.f + __expf(-x));
}
__device__ __forceinline__ float tanh_f(float x){
  float e = __expf(-2.f * x);
  return (1.f - e) / (1.f + e);
}

// async-stage KB x 1KB chunks of a ring slot into LDS (wave q takes chunks
// q, q+4, ...). Per-lane global src; wave-uniform LDS dest (+lane*16 by HW).
template<int KB>
__device__ __forceinline__ void stageN(unsigned* ldsbase, const void* gbase, int lane, int q){
  const char* g = (const char*)gbase;
  #pragma unroll
  for (int c = 0; c < KB / 4; ++c){
    int cc = q + c * 4;
    __builtin_amdgcn_global_load_lds((const unsigned*)(g + (size_t)cc * 1024 + lane * 16),
                                     ldsbase + cc * 256, 16, 0, 0);
  }
}

// ---------------- elementwise / gather kernels ----------------

__global__ void f2b_k(const float* __restrict__ s, u16* __restrict__ d, int n){
  int i = blockIdx.x * 256 + threadIdx.x;
  if (i < n) d[i] = f2b(s[i]);
}

__global__ void gather_xc_k(const float* __restrict__ mo, const float* __restrict__ lxm,
                            u16* __restrict__ xc, u16* __restrict__ pre_mo){
  int i = blockIdx.x * 256 + threadIdx.x;
  if (i >= 32 * 384) return;
  int n = i / 384, c = i - n * 384;
  float v = (c < 256) ? mo[(size_t)(n * 256 + c) * 600 + 29]
                      : lxm[(size_t)(n * 128 + (c - 256)) * 20];
  u16 h = f2b(v);
  xc[i] = h;
  if (c < 256) pre_mo[n * 256 + c] = h;
}

__global__ void lxm_g_k(const float* __restrict__ lxm, u16* __restrict__ o){
  int i = blockIdx.x * 256 + threadIdx.x;
  if (i >= 18 * 32 * 128) return;
  int c = i & 127, rest = i >> 7;
  int n = rest & 31, b = rest >> 5;
  o[i] = f2b(lxm[(size_t)(n * 128 + c) * 20 + 1 + b]);
}

__global__ void split_h_k(const float* __restrict__ hraw, u16* __restrict__ h0, u16* __restrict__ h1,
                          float* __restrict__ h0f, float* __restrict__ h1f){
  int i = blockIdx.x * 256 + threadIdx.x;
  if (i >= 32 * 1024) return;
  int n = i >> 10, c = i & 1023;
  float a = hraw[(size_t)n * 2048 + c];
  float b = hraw[(size_t)n * 2048 + 1024 + c];
  h0[i] = f2b(a); h1[i] = f2b(b);
  h0f[i] = a;     h1f[i] = b;
}

__global__ void build_xc0_k(const u16* __restrict__ pre_mo, const u16* __restrict__ aud_seq,
                            const u16* __restrict__ lxm_b, u16* __restrict__ xc0){
  int i = blockIdx.x * 256 + threadIdx.x;
  if (i >= 32 * 640) return;
  int n = i / 640, c = i - n * 640;
  u16 v;
  if (c < 256) v = pre_mo[n * 256 + c];
  else if (c < 512) v = aud_seq[n * 256 + (c - 256)];
  else v = lxm_b[n * 128 + (c - 512)];
  xc0[i] = v;
}

// repack linear [32][1024] bf16 into the swizzled ring-slot layout
__global__ void swz_emb_k(const u16* __restrict__ src, u16* __restrict__ dst){
  int i = blockIdx.x * 256 + threadIdx.x;
  if (i >= 32 * 1024) return;
  int row = i >> 10, col = i & 1023;
  unsigned boff = (unsigned)(row * 2048) + (((unsigned)col * 2) ^ ((row & 7) << 4));
  *(u16*)((char*)dst + boff) = src[i];
}

__global__ void t_wpT_k(const float* __restrict__ wp, u16* __restrict__ wpT){
  int i = blockIdx.x * 256 + threadIdx.x;
  if (i >= 1024 * 256) return;
  int h = i >> 8, j = i & 255;
  wpT[i] = f2b(wp[(size_t)j * 1024 + h]);
}

__global__ void foldW_k(const float* __restrict__ src, const float* __restrict__ g,
                        const float* __restrict__ b, const float* __restrict__ addb,
                        u16* __restrict__ Wg, float* __restrict__ S, float* __restrict__ B, int R){
  int row = blockIdx.x * 4 + (threadIdx.x >> 6);
  if (row >= R) return;
  int lane = threadIdx.x & 63;
  const float* sr = src + (size_t)row * 1024;
  float s = 0.f, bb = 0.f;
  #pragma unroll
  for (int k = 0; k < 16; ++k){
    int c = lane + k * 64;
    float w = sr[c], gw = w * g[c];
    Wg[(size_t)row * 1024 + c] = f2b(gw);
    s += gw; bb += w * b[c];
  }
  #pragma unroll
  for (int m = 1; m < 64; m <<= 1){ s += __shfl_xor(s, m); bb += __shfl_xor(bb, m); }
  if (lane == 0){ S[row] = s; B[row] = bb + (addb ? addb[row] : 0.f); }
}

__global__ void vfold_k(const float* __restrict__ W, int ldw, int off, const float* __restrict__ pb,
                        const float* __restrict__ base, float* __restrict__ v, int R){
  int row = blockIdx.x * 4 + (threadIdx.x >> 6);
  if (row >= R) return;
  int lane = threadIdx.x & 63;
  const float* wr = W + (size_t)row * ldw + off;
  float s = 0.f;
  #pragma unroll
  for (int k = 0; k < 4; ++k){ int j = lane + k * 64; s += wr[j] * pb[j]; }
  #pragma unroll
  for (int m = 1; m < 64; m <<= 1) s += __shfl_xor(s, m);
  if (lane == 0) v[row] = s + (base ? base[row] : 0.f);
}

// ---------------- im2col kernels ----------------

__global__ void im2col0_k(const float* __restrict__ aud, u16* __restrict__ A, int row0, long long tot){
  long long i = (long long)blockIdx.x * 256 + threadIdx.x;
  if (i >= tot) return;
  int k = (int)(i % 896);
  int row = row0 + (int)(i / 896);
  int ci = k / 7, kk = k - ci * 7;
  int p = row % 84, bn = row / 84;
  int b = bn >> 5, n = bn & 31;
  A[i] = f2b(aud[(size_t)(n * 128 + ci) * 600 + b * 30 + p + kk]);
}

__global__ void im2col1_k(const u16* __restrict__ O0, u16* __restrict__ A, int row0, long long tot){
  long long i = (long long)blockIdx.x * 256 + threadIdx.x;
  if (i >= tot) return;
  int k = (int)(i % 1280);
  int row = row0 + (int)(i / 1280);
  int ci = k / 5, kk = k - ci * 5;
  int p = row % 80, bn = row / 80;
  A[i] = O0[(size_t)(bn * 84 + p + kk) * 256 + ci];
}

__global__ void im2col2_k(const u16* __restrict__ O1, u16* __restrict__ A, int row0, long long tot){
  long long i = (long long)blockIdx.x * 256 + threadIdx.x;
  if (i >= tot) return;
  int k = (int)(i & 1023);
  int row = row0 + (int)(i >> 10);
  int ci = k >> 2, kk = k & 3;
  int p = row % 40, bn = row / 40;
  int pos = 2 * p - 1 + kk;
  A[i] = (pos >= 0 && pos < 80) ? O1[(size_t)(bn * 80 + pos) * 256 + ci] : (u16)0;
}

// ---------------- GEMM: C[M,N] = A[M,K] @ W[N,K]^T  (bf16 MFMA) ----------------

__global__ void gemm_bt(const u16* __restrict__ A, int lda,
                        const u16* __restrict__ W, int ldw, const float* __restrict__ bias,
                        void* __restrict__ outp, int M, int N, int K, int flags){
  const int lane = threadIdx.x & 63, widx = threadIdx.x >> 6;
  const int m0 = blockIdx.x * 64 + widx * 16;
  if (m0 >= M) return;
  const int n0 = blockIdx.y * 64;
  const int r = lane & 15, g4 = lane >> 4;
  const u16* arow = A + (size_t)(m0 + r) * lda + g4 * 8;
  const u16* wrow = W + (size_t)(n0 + r) * ldw + g4 * 8;
  f32x4 acc[4];
  const f32x4 FZ = {0.f, 0.f, 0.f, 0.f};
  acc[0] = FZ; acc[1] = FZ; acc[2] = FZ; acc[3] = FZ;
  for (int k = 0; k < K; k += 32){
    short8 a = ld8(arow + k);
    #pragma unroll
    for (int j = 0; j < 4; ++j)
      acc[j] = mfma16(a, ld8(wrow + (size_t)j * 16 * ldw + k), acc[j]);
  }
  #pragma unroll
  for (int j = 0; j < 4; ++j){
    int col = n0 + j * 16 + r;
    float bv = bias ? bias[col] : 0.f;
    #pragma unroll
    for (int q = 0; q < 4; ++q){
      int row = m0 + g4 * 4 + q;
      float v = acc[j][q] + bv;
      if (flags & GELU_FLG) v = gelu_f(v);
      if (flags & BF16_FLG) ((u16*)outp)[(size_t)row * N + col] = f2b(v);
      else                  ((float*)outp)[(size_t)row * N + col] = v;
    }
  }
}

// ---------------- encoder LayerNorm -> aud_seq (bf16) ----------------

__global__ void enc_ln_k(const float* __restrict__ O3, const float* __restrict__ g,
                         const float* __restrict__ bb, u16* __restrict__ aud_seq){
  int rid = blockIdx.x * 4 + (threadIdx.x >> 6);
  int lane = threadIdx.x & 63;
  int b = rid / 960, rem = rid - b * 960;
  int p2 = rem >> 5, n = rem & 31;
  int orow = (b * 32 + n) * 40 + p2;
  const float4 v = *reinterpret_cast<const float4*>(O3 + (size_t)orow * 256 + lane * 4);
  float s  = v.x + v.y + v.z + v.w;
  float s2 = v.x * v.x + v.y * v.y + v.z * v.z + v.w * v.w;
  #pragma unroll
  for (int m = 1; m < 64; m <<= 1){ s += __shfl_xor(s, m); s2 += __shfl_xor(s2, m); }
  float mu = s * (1.f / 256.f);
  float var = s2 * (1.f / 256.f) - mu * mu;
  float rs = rsqrtf(var + 1e-5f);
  int c = lane * 4;
  u16* dst = aud_seq + (size_t)rid * 256 + c;
  dst[0] = f2b((v.x - mu) * rs * g[c + 0] + bb[c + 0]);
  dst[1] = f2b((v.y - mu) * rs * g[c + 1] + bb[c + 1]);
  dst[2] = f2b((v.z - mu) * rs * g[c + 2] + bb[c + 2]);
  dst[3] = f2b((v.w - mu) * rs * g[c + 3] + bb[c + 3]);
}

// ---------------- persistent weight-stationary dataflow decoder ----------------

struct DecArgs {
  const u16 *aud_seq, *lxm_b;
  const u16 *wih0, *whh0, *wih1, *whh1, *wd;
  const u16 *wpg, *Wdpg, *Wgpg;
  const float *Sp, *Bp, *S1, *B1, *S2, *B2, *vX, *vG;
  const float *bih0, *bhh0, *bih1, *bhh1;
  const u16 *h0init, *h1init;
  u16 *embR, *h0R, *h1R;                 // rings: slot t = 32x1024 bf16 (64 KB, SWIZZLED)
  float *statsR;                         // ring:  slot t = [64 blk][64] f32
  float *GxR, *XalR, *GalR;              // mod-8 rings (poll-gated reuse)
  float *h0f, *h1f, *out;
  int *sync;                             // slots[4][128][16]
};

// producer: drain stores, then publish epoch on own private slot line
__device__ __forceinline__ void sigslot(int* slot, int ep){
  asm volatile("s_waitcnt vmcnt(0)" ::: "memory");
  __syncthreads();
  if (threadIdx.x == 0)
    __hip_atomic_store(slot, ep, __ATOMIC_RELAXED, __HIP_MEMORY_SCOPE_AGENT);
}
// consumer: wave 0 polls the producer group's slots directly (lane i <-> slot i;
// lanes < nx additionally check slotE). __all + syncthreads releases the block.
__device__ __forceinline__ void wait_grp(const int* slotG, int nx, const int* slotE, int tgt){
  if (threadIdx.x < 64){
    const int lane = threadIdx.x;
    for (;;){
      int v = __hip_atomic_load(slotG + lane * 16, __ATOMIC_RELAXED, __HIP_MEMORY_SCOPE_AGENT);
      bool ok = (v >= tgt);
      if (lane < nx){
        int v2 = __hip_atomic_load(slotE + lane * 16, __ATOMIC_RELAXED, __HIP_MEMORY_SCOPE_AGENT);
        ok = ok && (v2 >= tgt);
      }
      if (__all(ok)) break;
      __builtin_amdgcn_s_sleep(1);
    }
  }
  __syncthreads();
}
__device__ __forceinline__ void stage_fence(){
  asm volatile("s_waitcnt vmcnt(0)" ::: "memory");
  __syncthreads();
}

__global__ __launch_bounds__(256, 1) void decode_k(DecArgs A){
  const int tid = threadIdx.x;
  const int lane = tid & 63, q = tid >> 6;
  const int r = lane & 15, g4 = lane >> 4;
  const int blk = blockIdx.x;
  __shared__ __align__(16) unsigned smw[25088];   // 64KB staging + 34.8KB exch/stats
  char* const stg = (char*)smw;
  float* const exch = (float*)(smw + 16384);      // L0/L1: [4][4][32][17]
  float* const stgStats = (float*)(smw + 16384);  // PE: 16KB stats staging
  const f32x4 FZ = {0.f, 0.f, 0.f, 0.f};
  const int sw = (r & 7) << 4;
  int* const slotH0 = A.sync;
  int* const slotH1 = A.sync + 128 * 16;
  int* const slotPE = A.sync + 256 * 16;
  int* const slotAL = A.sync + 384 * 16;

  if (blk < 64){
    // ---------------- L0: h0 producer ----------------
    const int c0 = blk * 16;
    const int kq = q * 256;
    int* const mySlot = slotH0 + blk * 16;
    short8 we[24], wh[24];
    #pragma unroll
    for (int g = 0; g < 3; ++g)
      #pragma unroll
      for (int ch = 0; ch < 8; ++ch){
        we[g * 8 + ch] = ld8(A.wih0 + (size_t)(g * 1024 + c0 + r) * 1664 + kq + ch * 32 + g4 * 8);
        wh[g * 8 + ch] = ld8(A.whh0 + (size_t)(g * 1024 + c0 + r) * 1024 + kq + ch * 32 + g4 * 8);
      }
    const int n_c = tid >> 3;
    const int cc0 = (tid & 7) * 2;
    const int colA = c0 + cc0, colB = colA + 1;
    const unsigned stoff = (unsigned)(n_c * 2048) + (((unsigned)colA * 2) ^ ((n_c & 7) << 4));
    const float bi_r[2] = {A.bih0[colA], A.bih0[colB]};
    const float bi_z[2] = {A.bih0[1024 + colA], A.bih0[1024 + colB]};
    const float bi_n[2] = {A.bih0[2048 + colA], A.bih0[2048 + colB]};
    const float bh_r[2] = {A.bhh0[colA], A.bhh0[colB]};
    const float bh_z[2] = {A.bhh0[1024 + colA], A.bhh0[1024 + colB]};
    const float bh_n[2] = {A.bhh0[2048 + colA], A.bhh0[2048 + colB]};
    f32x4 ar[2], az[2], ani[2], anh[2];
    ar[0] = FZ; ar[1] = FZ; az[0] = FZ; az[1] = FZ; ani[0] = FZ; ani[1] = FZ; anh[0] = FZ; anh[1] = FZ;
    #pragma unroll
    for (int ch = 0; ch < 8; ++ch){
      short8 a0 = ld8(A.h0init + r * 1024 + kq + ch * 32 + g4 * 8);
      short8 a1 = ld8(A.h0init + (16 + r) * 1024 + kq + ch * 32 + g4 * 8);
      ar[0] = mfma16(a0, wh[ch], ar[0]);        ar[1] = mfma16(a1, wh[ch], ar[1]);
      az[0] = mfma16(a0, wh[8 + ch], az[0]);    az[1] = mfma16(a1, wh[8 + ch], az[1]);
      anh[0] = mfma16(a0, wh[16 + ch], anh[0]); anh[1] = mfma16(a1, wh[16 + ch], anh[1]);
    }
    #pragma unroll 1
    for (int t = 0; t < DEC_STEPS; ++t){
      if (t > 0) wait_grp(slotPE, 4, slotPE + 64 * 16, t);   // PE step t-1 done
      const u16*  embT = A.embR + (size_t)t * 32768;
      u16*        h0T  = A.h0R  + (size_t)t * 32768;
      const float* GxT = A.GxR + (size_t)(t & 7) * 98304;
      stageN<64>(smw, embT, lane, q);
      float pgr[2], pgz[2], pgn[2], phf[2];
      #pragma unroll
      for (int e = 0; e < 2; ++e){
        int col = c0 + cc0 + e;
        pgr[e] = ldfc(GxT + n_c * 3072 + col);
        pgz[e] = ldfc(GxT + n_c * 3072 + 1024 + col);
        pgn[e] = ldfc(GxT + n_c * 3072 + 2048 + col);
        phf[e] = A.h0f[n_c * 1024 + col];
      }
      stage_fence();
      #pragma unroll
      for (int ch = 0; ch < 8; ++ch){
        int off = ((kq + ch * 32 + g4 * 8) * 2) ^ sw;
        short8 a0 = lds8(stg + r * 2048 + off);
        short8 a1 = lds8(stg + (16 + r) * 2048 + off);
        ar[0] = mfma16(a0, we[ch], ar[0]);        ar[1] = mfma16(a1, we[ch], ar[1]);
        az[0] = mfma16(a0, we[8 + ch], az[0]);    az[1] = mfma16(a1, we[8 + ch], az[1]);
        ani[0] = mfma16(a0, we[16 + ch], ani[0]); ani[1] = mfma16(a1, we[16 + ch], ani[1]);
      }
      #pragma unroll
      for (int m = 0; m < 2; ++m)
        #pragma unroll
        for (int j = 0; j < 4; ++j){
          int row = m * 16 + g4 * 4 + j;
          exch[((q * 4 + 0) * 32 + row) * 17 + r] = ar[m][j];
          exch[((q * 4 + 1) * 32 + row) * 17 + r] = az[m][j];
          exch[((q * 4 + 2) * 32 + row) * 17 + r] = ani[m][j];
          exch[((q * 4 + 3) * 32 + row) * 17 + r] = anh[m][j];
        }
      __syncthreads();
      float hv2[2];
      #pragma unroll
      for (int e = 0; e < 2; ++e){
        int cc = cc0 + e, col = c0 + cc;
        float sr = bi_r[e] + bh_r[e] + pgr[e];
        float sz = bi_z[e] + bh_z[e] + pgz[e];
        float si = bi_n[e] + pgn[e];
        float sh = bh_n[e];
        #pragma unroll
        for (int qq = 0; qq < 4; ++qq){
          sr += exch[((qq * 4 + 0) * 32 + n_c) * 17 + cc];
          sz += exch[((qq * 4 + 1) * 32 + n_c) * 17 + cc];
          si += exch[((qq * 4 + 2) * 32 + n_c) * 17 + cc];
          sh += exch[((qq * 4 + 3) * 32 + n_c) * 17 + cc];
        }
        float rg = sigmoid_f(sr), zg = sigmoid_f(sz);
        float ng = tanh_f(si + rg * sh);
        float hv = (1.f - zg) * ng + zg * phf[e];
        A.h0f[n_c * 1024 + col] = hv;
        hv2[e] = hv;
      }
      stu32c((char*)h0T + stoff,
             (unsigned)f2b(hv2[0]) | ((unsigned)f2b(hv2[1]) << 16));
      __syncthreads();
      sigslot(mySlot, t + 1);
      wait_grp(slotH0, 0, slotH0, t + 1);        // full h0[t] for gh0-next
      stageN<64>(smw, h0T, lane, q);
      stage_fence();
      ar[0] = FZ; ar[1] = FZ; az[0] = FZ; az[1] = FZ; ani[0] = FZ; ani[1] = FZ; anh[0] = FZ; anh[1] = FZ;
      #pragma unroll
      for (int ch = 0; ch < 8; ++ch){
        int off = ((kq + ch * 32 + g4 * 8) * 2) ^ sw;
        short8 a0 = lds8(stg + r * 2048 + off);
        short8 a1 = lds8(stg + (16 + r) * 2048 + off);
        ar[0] = mfma16(a0, wh[ch], ar[0]);        ar[1] = mfma16(a1, wh[ch], ar[1]);
        az[0] = mfma16(a0, wh[8 + ch], az[0]);    az[1] = mfma16(a1, wh[8 + ch], az[1]);
        anh[0] = mfma16(a0, wh[16 + ch], anh[0]); anh[1] = mfma16(a1, wh[16 + ch], anh[1]);
      }
    }
  } else if (blk < 128){
    // ---------------- L1: h1 producer ----------------
    const int c0 = (blk - 64) * 16;
    const int kq = q * 256;
    int* const mySlot = slotH1 + (blk - 64) * 16;
    short8 wi[24], wh[24];
    #pragma unroll
    for (int g = 0; g < 3; ++g)
      #pragma unroll
      for (int ch = 0; ch < 8; ++ch){
        wi[g * 8 + ch] = ld8(A.wih1 + (size_t)(g * 1024 + c0 + r) * 1024 + kq + ch * 32 + g4 * 8);
        wh[g * 8 + ch] = ld8(A.whh1 + (size_t)(g * 1024 + c0 + r) * 1024 + kq + ch * 32 + g4 * 8);
      }
    const int n_c = tid >> 3;
    const int cc0 = (tid & 7) * 2;
    const int colA = c0 + cc0, colB = colA + 1;
    const unsigned stoff = (unsigned)(n_c * 2048) + (((unsigned)colA * 2) ^ ((n_c & 7) << 4));
    const float bi_r[2] = {A.bih1[colA], A.bih1[colB]};
    const float bi_z[2] = {A.bih1[1024 + colA], A.bih1[1024 + colB]};
    const float bi_n[2] = {A.bih1[2048 + colA], A.bih1[2048 + colB]};
    const float bh_r[2] = {A.bhh1[colA], A.bhh1[colB]};
    const float bh_z[2] = {A.bhh1[1024 + colA], A.bhh1[1024 + colB]};
    const float bh_n[2] = {A.bhh1[2048 + colA], A.bhh1[2048 + colB]};
    f32x4 ar[2], az[2], ani[2], anh[2];
    ar[0] = FZ; ar[1] = FZ; az[0] = FZ; az[1] = FZ; ani[0] = FZ; ani[1] = FZ; anh[0] = FZ; anh[1] = FZ;
    #pragma unroll
    for (int ch = 0; ch < 8; ++ch){
      short8 a0 = ld8(A.h1init + r * 1024 + kq + ch * 32 + g4 * 8);
      short8 a1 = ld8(A.h1init + (16 + r) * 1024 + kq + ch * 32 + g4 * 8);
      ar[0] = mfma16(a0, wh[ch], ar[0]);        ar[1] = mfma16(a1, wh[ch], ar[1]);
      az[0] = mfma16(a0, wh[8 + ch], az[0]);    az[1] = mfma16(a1, wh[8 + ch], az[1]);
      anh[0] = mfma16(a0, wh[16 + ch], anh[0]); anh[1] = mfma16(a1, wh[16 + ch], anh[1]);
    }
    #pragma unroll 1
    for (int t = 0; t < DEC_STEPS; ++t){
      wait_grp(slotH0, 0, slotH0, t + 1);        // h0[t] ready
      const u16* h0T = A.h0R + (size_t)t * 32768;
      u16*       h1T = A.h1R + (size_t)t * 32768;
      stageN<64>(smw, h0T, lane, q);
      float phf[2];
      phf[0] = A.h1f[n_c * 1024 + colA];
      phf[1] = A.h1f[n_c * 1024 + colB];
      stage_fence();
      #pragma unroll
      for (int ch = 0; ch < 8; ++ch){
        int off = ((kq + ch * 32 + g4 * 8) * 2) ^ sw;
        short8 a0 = lds8(stg + r * 2048 + off);
        short8 a1 = lds8(stg + (16 + r) * 2048 + off);
        ar[0] = mfma16(a0, wi[ch], ar[0]);        ar[1] = mfma16(a1, wi[ch], ar[1]);
        az[0] = mfma16(a0, wi[8 + ch], az[0]);    az[1] = mfma16(a1, wi[8 + ch], az[1]);
        ani[0] = mfma16(a0, wi[16 + ch], ani[0]); ani[1] = mfma16(a1, wi[16 + ch], ani[1]);
      }
      #pragma unroll
      for (int m = 0; m < 2; ++m)
        #pragma unroll
        for (int j = 0; j < 4; ++j){
          int row = m * 16 + g4 * 4 + j;
          exch[((q * 4 + 0) * 32 + row) * 17 + r] = ar[m][j];
          exch[((q * 4 + 1) * 32 + row) * 17 + r] = az[m][j];
          exch[((q * 4 + 2) * 32 + row) * 17 + r] = ani[m][j];
          exch[((q * 4 + 3) * 32 + row) * 17 + r] = anh[m][j];
        }
      __syncthreads();
      float hv2[2];
      #pragma unroll
      for (int e = 0; e < 2; ++e){
        int cc = cc0 + e, col = c0 + cc;
        float sr = bi_r[e] + bh_r[e];
        float sz = bi_z[e] + bh_z[e];
        float si = bi_n[e];
        float sh = bh_n[e];
        #pragma unroll
        for (int qq = 0; qq < 4; ++qq){
          sr += exch[((qq * 4 + 0) * 32 + n_c) * 17 + cc];
          sz += exch[((qq * 4 + 1) * 32 + n_c) * 17 + cc];
          si += exch[((qq * 4 + 2) * 32 + n_c) * 17 + cc];
          sh += exch[((qq * 4 + 3) * 32 + n_c) * 17 + cc];
        }
        float rg = sigmoid_f(sr), zg = sigmoid_f(sz);
        float ng = tanh_f(si + rg * sh);
        float hv = (1.f - zg) * ng + zg * phf[e];
        A.h1f[n_c * 1024 + col] = hv;
        hv2[e] = hv;
      }
      stu32c((char*)h1T + stoff,
             (unsigned)f2b(hv2[0]) | ((unsigned)f2b(hv2[1]) << 16));
      float sv = hv2[0] + hv2[1], sq = hv2[0] * hv2[0] + hv2[1] * hv2[1];
      sv += __shfl_xor(sv, 1); sq += __shfl_xor(sq, 1);
      sv += __shfl_xor(sv, 2); sq += __shfl_xor(sq, 2);
      sv += __shfl_xor(sv, 4); sq += __shfl_xor(sq, 4);
      if ((tid & 7) == 0){
        stfc(A.statsR + (size_t)t * 4096 + (blk - 64) * 64 + n_c, sv);
        stfc(A.statsR + (size_t)t * 4096 + (blk - 64) * 64 + 32 + n_c, sq);
      }
      __syncthreads();
      sigslot(mySlot, t + 1);
      wait_grp(slotH1, 0, slotH1, t + 1);        // full h1[t] for gh1-next
      stageN<64>(smw, h1T, lane, q);
      stage_fence();
      ar[0] = FZ; ar[1] = FZ; az[0] = FZ; az[1] = FZ; ani[0] = FZ; ani[1] = FZ; anh[0] = FZ; anh[1] = FZ;
      #pragma unroll
      for (int ch = 0; ch < 8; ++ch){
        int off = ((kq + ch * 32 + g4 * 8) * 2) ^ sw;
        short8 a0 = lds8(stg + r * 2048 + off);
        short8 a1 = lds8(stg + (16 + r) * 2048 + off);
        ar[0] = mfma16(a0, wh[ch], ar[0]);        ar[1] = mfma16(a1, wh[ch], ar[1]);
        az[0] = mfma16(a0, wh[8 + ch], az[0]);    az[1] = mfma16(a1, wh[8 + ch], az[1]);
        anh[0] = mfma16(a0, wh[16 + ch], anh[0]); anh[1] = mfma16(a1, wh[16 + ch], anh[1]);
      }
    }
  } else if (blk < 196){
    // ---------------- PE: pred / emb_{t+1} / Gx_{t+1} ----------------
    const int tile = (blk - 128) * 4 + q;
    int* const mySlot = slotPE + (blk - 128) * 16;
    int jt, c0;
    const u16* wsrc; const float *Sv, *Bv;
    if (tile < 16)      { jt = 0; c0 = tile * 16;        wsrc = A.wpg;  Sv = A.Sp; Bv = A.Bp; }
    else if (tile < 80) { jt = 1; c0 = (tile - 16) * 16; wsrc = A.Wdpg; Sv = A.S1; Bv = A.B1; }
    else                { jt = 2; c0 = (tile - 80) * 16; wsrc = A.Wgpg; Sv = A.S2; Bv = A.B2; }
    short8 w[32];
    #pragma unroll
    for (int ch = 0; ch < 32; ++ch)
      w[ch] = ld8(wsrc + (size_t)(c0 + r) * 1024 + ch * 32 + g4 * 8);
    const float Sc = Sv[c0 + r], Bc = Bv[c0 + r];
    const int col = c0 + r;
    #pragma unroll 1
    for (int t = 0; t < DEC_STEPS; ++t){
      wait_grp(slotH1, 16, slotAL, t + 1);       // h1[t]+stats[t] AND Xal/Gal[t+1]
      const u16*   h1T = A.h1R + (size_t)t * 32768;
      const float* stT = A.statsR + (size_t)t * 4096;
      const int sl = (t + 1) & 7;
      stageN<64>(smw, h1T, lane, q);
      stageN<16>(smw + 16384, stT, lane, q);
      const float* XalT = A.XalR + (size_t)sl * 32768;
      const float* GalT = A.GalR + (size_t)sl * 98304;
      float addv[2][4];
      #pragma unroll
      for (int m = 0; m < 2; ++m)
        #pragma unroll
        for (int j = 0; j < 4; ++j){
          int n = m * 16 + g4 * 4 + j;
          addv[m][j] = (jt == 1) ? ldfc(XalT + n * 1024 + col)
                     : (jt == 2) ? ldfc(GalT + n * 3072 + col) : 0.f;
        }
      stage_fence();
      float sacc = 0.f;
      #pragma unroll
      for (int b2 = 0; b2 < 64; ++b2) sacc += stgStats[b2 * 64 + lane];
      float muA[2][4], rsA[2][4];
      #pragma unroll
      for (int m = 0; m < 2; ++m)
        #pragma unroll
        for (int j = 0; j < 4; ++j){
          int n = m * 16 + g4 * 4 + j;
          float sv = __shfl(sacc, n), sq = __shfl(sacc, 32 + n);
          float mu = sv * (1.f / 1024.f);
          muA[m][j] = mu;
          rsA[m][j] = rsqrtf(sq * (1.f / 1024.f) - mu * mu + 1e-5f);
        }
      f32x4 a0 = FZ, a1 = FZ;
      #pragma unroll
      for (int ch = 0; ch < 32; ++ch){
        int off = ((ch * 32 + g4 * 8) * 2) ^ sw;
        short8 x0 = lds8(stg + r * 2048 + off);
        short8 x1 = lds8(stg + (16 + r) * 2048 + off);
        a0 = mfma16(x0, w[ch], a0);
        a1 = mfma16(x1, w[ch], a1);
      }
      u16*   embN = A.embR + (size_t)(t + 1) * 32768;
      float* GxN  = A.GxR + (size_t)sl * 98304;
      #pragma unroll
      for (int m = 0; m < 2; ++m)
        #pragma unroll
        for (int j = 0; j < 4; ++j){
          int n = m * 16 + g4 * 4 + j;
          float acc = (m ? a1[j] : a0[j]);
          float v = rsA[m][j] * (acc - muA[m][j] * Sc) + Bc;
          if (jt == 0){
            A.out[(size_t)n * (256 * 540) + (size_t)col * 540 + t] = v;
          } else if (jt == 1){
            float pre = v + addv[m][j];
            unsigned boff = (unsigned)(n * 2048) + (((unsigned)col * 2) ^ ((n & 7) << 4));
            st16c((u16*)((char*)embN + boff), (unsigned)f2b(gelu_f(pre)));
          } else {
            stfc(GxN + n * 3072 + col, v + addv[m][j]);
          }
        }
      sigslot(mySlot, t + 1);
    }
  } else {
    // ---------------- AL: audio/lxm partials for step t+1 ----------------
    const int wg = (blk - 196) * 4 + q;
    int* const mySlot = slotAL + (blk - 196) * 16;
    const int at0 = wg * 4;
    short8 w[48];
    float vb[4];
    #pragma unroll
    for (int j = 0; j < 4; ++j){
      int at = at0 + j;
      if (at < 64){
        #pragma unroll
        for (int ch = 0; ch < 12; ++ch)
          w[j * 12 + ch] = ld8(A.wd + (size_t)(at * 16 + r) * 640 + 256 + ch * 32 + g4 * 8);
        vb[j] = A.vX[at * 16 + r];
      } else {
        #pragma unroll
        for (int ch = 0; ch < 12; ++ch)
          w[j * 12 + ch] = ld8(A.wih0 + (size_t)((at - 64) * 16 + r) * 1664 + 1280 + ch * 32 + g4 * 8);
        vb[j] = A.vG[(at - 64) * 16 + r];
      }
    }
    #pragma unroll 1
    for (int t = 0; t < DEC_STEPS; ++t){
      if (t >= 8) wait_grp(slotPE, 4, slotPE + 64 * 16, t - 7);  // slot (t+1)&7 free
      const int tn = t + 1;
      const int tread = (tn > 539) ? 539 : tn;
      const int bn = tread / 30;
      const int sl = tn & 7;
      float* XalW = A.XalR + (size_t)sl * 32768;
      float* GalW = A.GalR + (size_t)sl * 98304;
      short8 af0[12], af1[12];
      #pragma unroll
      for (int ch = 0; ch < 12; ++ch){
        int kk = ch * 32 + g4 * 8;
        if (ch < 8){
          af0[ch] = ld8(A.aud_seq + ((size_t)tread * 32 + r) * 256 + kk);
          af1[ch] = ld8(A.aud_seq + ((size_t)tread * 32 + 16 + r) * 256 + kk);
        } else {
          af0[ch] = ld8(A.lxm_b + ((size_t)bn * 32 + r) * 128 + kk - 256);
          af1[ch] = ld8(A.lxm_b + ((size_t)bn * 32 + 16 + r) * 128 + kk - 256);
        }
      }
      #pragma unroll
      for (int j = 0; j < 4; ++j){
        f32x4 c0a = FZ, c1a = FZ;
        #pragma unroll
        for (int ch = 0; ch < 12; ++ch){
          c0a = mfma16(af0[ch], w[j * 12 + ch], c0a);
          c1a = mfma16(af1[ch], w[j * 12 + ch], c1a);
        }
        int at = at0 + j;
        #pragma unroll
        for (int m = 0; m < 2; ++m)
          #pragma unroll
          for (int jj = 0; jj < 4; ++jj){
            int n = m * 16 + g4 * 4 + jj;
            float v = (m ? c1a[jj] : c0a[jj]) + vb[j];
            if (at < 64) stfc(XalW + n * 1024 + at * 16 + r, v);
            else         stfc(GalW + n * 3072 + (at - 64) * 16 + r, v);
          }
      }
      sigslot(mySlot, tn);
    }
  }
}

// ---------------------------------------------------------------------------

extern "C" void kernel_launch(void* const* d_in, const int* in_sizes, int n_in,
                              void* d_out, int out_size, void* d_ws, size_t ws_size,
                              hipStream_t stream) {
  enum { I_AUD=0, I_MO=1, I_LXM=2, I_AEW0=3, I_AEB0=4, I_AEW1=5, I_AEB1=6, I_AEW2=7, I_AEB2=8,
         I_AEW3=9, I_AEB3=10, I_AELNG=11, I_AELNB=12, I_CIW0=13, I_CIB0=14, I_CIW1=15, I_CIB1=16,
         I_CIW2=17, I_CIB2=18, I_DECW=19, I_DECB=20, I_WIH0=21, I_WHH0=22, I_BIH0=23, I_BHH0=24,
         I_WIH1=25, I_WHH1=26, I_BIH1=27, I_BHH1=28, I_LNG=29, I_LNB=30, I_PREDW=31, I_PREDB=32 };

  char* base = (char*)d_ws;
  size_t off = 0;
  auto alloc = [&](size_t bytes)->void*{
    void* p = base + off;
    off += (bytes + 255) & ~(size_t)255;
    return p;
  };

  u16* wd_b   = (u16*)alloc((size_t)1024*640*2);
  u16* wih0_b = (u16*)alloc((size_t)3072*1664*2);
  u16* whh0_b = (u16*)alloc((size_t)3072*1024*2);
  u16* wih1_b = (u16*)alloc((size_t)3072*1024*2);
  u16* whh1_b = (u16*)alloc((size_t)3072*1024*2);
  u16* wc0    = (u16*)alloc((size_t)1024*384*2);
  u16* wc1    = (u16*)alloc((size_t)1024*1024*2);
  u16* wc2    = (u16*)alloc((size_t)2048*1024*2);
  u16* w0k    = (u16*)alloc((size_t)256*896*2);
  u16* w1k    = (u16*)alloc((size_t)256*1280*2);
  u16* w2k    = (u16*)alloc((size_t)256*1024*2);
  u16* w3k    = (u16*)alloc((size_t)256*256*2);
  u16* wpT    = (u16*)alloc((size_t)1024*256*2);
  u16* wpg    = (u16*)alloc((size_t)256*1024*2);
  u16* Wdpg   = (u16*)alloc((size_t)1024*1024*2);
  u16* Wgpg   = (u16*)alloc((size_t)3072*1024*2);
  float* Sp = (float*)alloc(256*4);   float* Bp = (float*)alloc(256*4);
  float* S1 = (float*)alloc(1024*4);  float* B1 = (float*)alloc(1024*4);
  float* S2 = (float*)alloc(3072*4);  float* B2 = (float*)alloc(3072*4);
  float* vX = (float*)alloc(1024*4);  float* vG = (float*)alloc(3072*4);
  u16* aud_seq = (u16*)alloc((size_t)540*32*256*2);
  u16* lxm_b   = (u16*)alloc((size_t)18*32*128*2);
  u16* xc      = (u16*)alloc((size_t)32*384*2);
  u16* xc0     = (u16*)alloc((size_t)32*640*2);
  u16* ci1     = (u16*)alloc((size_t)32*1024*2);
  u16* ci2     = (u16*)alloc((size_t)32*1024*2);
  float* hraw  = (float*)alloc((size_t)32*2048*4);
  u16* h0i     = (u16*)alloc((size_t)32*1024*2);
  u16* h1i     = (u16*)alloc((size_t)32*1024*2);
  float* h0f   = (float*)alloc((size_t)32*1024*4);
  float* h1f   = (float*)alloc((size_t)32*1024*4);
  u16* pre_mo  = (u16*)alloc((size_t)32*256*2);
  u16* emb0    = (u16*)alloc((size_t)32*1024*2);
  float* GxR   = (float*)alloc((size_t)8*32*3072*4);
  float* XalR  = (float*)alloc((size_t)8*32*1024*4);
  float* GalR  = (float*)alloc((size_t)8*32*3072*4);
  int* syncb   = (int*)alloc((size_t)512*16*4);      // slots only (32 KB)
  char* enc_base = base + off;
  u16* O0   = (u16*)alloc((size_t)48384*256*2);
  u16* O1   = (u16*)alloc((size_t)46080*256*2);
  u16* O2   = (u16*)alloc((size_t)23040*256*2);
  float* O3 = (float*)alloc((size_t)23040*256*4);
  u16* Abuf = (u16*)alloc((size_t)23040*1280*2);
  float* Wdp_f = (float*)Abuf;
  float* Wgp_f = (float*)((char*)Abuf + (size_t)1024*1024*4 + 256);
  u16* embR     = (u16*)enc_base;
  u16* h0R      = embR + (size_t)541*32768;
  u16* h1R      = h0R + (size_t)540*32768;
  float* statsR = (float*)(h1R + (size_t)540*32768);
  (void)ws_size; (void)in_sizes; (void)n_in; (void)out_size;

  const float* aud = (const float*)d_in[I_AUD];
  const float* mo  = (const float*)d_in[I_MO];
  const float* lxm = (const float*)d_in[I_LXM];
  float* out = (float*)d_out;

  auto cdiv = [](long long a, long long b)->int{ return (int)((a + b - 1) / b); };
  auto cvt = [&](int idx, u16* dst, int n){
    f2b_k<<<cdiv(n,256), 256, 0, stream>>>((const float*)d_in[idx], dst, n);
  };

  cvt(I_DECW, wd_b,   1024*640);
  cvt(I_WIH0, wih0_b, 3072*1664);
  cvt(I_WHH0, whh0_b, 3072*1024);
  cvt(I_WIH1, wih1_b, 3072*1024);
  cvt(I_WHH1, whh1_b, 3072*1024);
  cvt(I_CIW0, wc0,    1024*384);
  cvt(I_CIW1, wc1,    1024*1024);
  cvt(I_CIW2, wc2,    2048*1024);
  cvt(I_AEW0, w0k,    256*896);
  cvt(I_AEW1, w1k,    256*1280);
  cvt(I_AEW2, w2k,    256*1024);
  cvt(I_AEW3, w3k,    256*256);

  for (int c = 0; c < 2; ++c){
    int row0 = c * 24192;
    long long tot = (long long)24192 * 896;
    im2col0_k<<<cdiv(tot,256), 256, 0, stream>>>(aud, Abuf, row0, tot);
    gemm_bt<<<dim3(24192/64, 4), 256, 0, stream>>>(Abuf, 896, w0k, 896, (const float*)d_in[I_AEB0],
        O0 + (size_t)row0*256, 24192, 256, 896, GELU_FLG|BF16_FLG);
  }
  for (int c = 0; c < 2; ++c){
    int row0 = c * 23040;
    long long tot = (long long)23040 * 1280;
    im2col1_k<<<cdiv(tot,256), 256, 0, stream>>>(O0, Abuf, row0, tot);
    gemm_bt<<<dim3(23040/64, 4), 256, 0, stream>>>(Abuf, 1280, w1k, 1280, (const float*)d_in[I_AEB1],
        O1 + (size_t)row0*256, 23040, 256, 1280, GELU_FLG|BF16_FLG);
  }
  {
    long long tot = (long long)23040 * 1024;
    im2col2_k<<<cdiv(tot,256), 256, 0, stream>>>(O1, Abuf, 0, tot);
    gemm_bt<<<dim3(23040/64, 4), 256, 0, stream>>>(Abuf, 1024, w2k, 1024, (const float*)d_in[I_AEB2],
        O2, 23040, 256, 1024, GELU_FLG|BF16_FLG);
  }
  gemm_bt<<<dim3(23040/64, 4), 256, 0, stream>>>(O2, 256, w3k, 256, (const float*)d_in[I_AEB3],
      O3, 23040, 256, 256, GELU_FLG);
  enc_ln_k<<<4320, 256, 0, stream>>>(O3, (const float*)d_in[I_AELNG], (const float*)d_in[I_AELNB], aud_seq);

  lxm_g_k<<<cdiv(18*32*128,256), 256, 0, stream>>>(lxm, lxm_b);
  gather_xc_k<<<cdiv(32*384,256), 256, 0, stream>>>(mo, lxm, xc, pre_mo);
  gemm_bt<<<dim3(1,16), 256, 0, stream>>>(xc, 384, wc0, 384, (const float*)d_in[I_CIB0],
      ci1, 32, 1024, 384, GELU_FLG|BF16_FLG);
  gemm_bt<<<dim3(1,16), 256, 0, stream>>>(ci1, 1024, wc1, 1024, (const float*)d_in[I_CIB1],
      ci2, 32, 1024, 1024, GELU_FLG|BF16_FLG);
  gemm_bt<<<dim3(1,32), 256, 0, stream>>>(ci2, 1024, wc2, 1024, (const float*)d_in[I_CIB2],
      hraw, 32, 2048, 1024, 0);
  split_h_k<<<cdiv(32*1024,256), 256, 0, stream>>>(hraw, h0i, h1i, h0f, h1f);

  t_wpT_k<<<cdiv(1024*256,256), 256, 0, stream>>>((const float*)d_in[I_PREDW], wpT);
  gemm_bt<<<dim3(16,16), 256, 0, stream>>>(wd_b, 640, wpT, 256, nullptr, Wdp_f, 1024, 1024, 256, 0);
  gemm_bt<<<dim3(48,16), 256, 0, stream>>>(wih0_b + 1024, 1664, wpT, 256, nullptr, Wgp_f, 3072, 1024, 256, 0);
  foldW_k<<<cdiv(1024,4), 256, 0, stream>>>(Wdp_f, (const float*)d_in[I_LNG], (const float*)d_in[I_LNB],
      nullptr, Wdpg, S1, B1, 1024);
  foldW_k<<<cdiv(3072,4), 256, 0, stream>>>(Wgp_f, (const float*)d_in[I_LNG], (const float*)d_in[I_LNB],
      nullptr, Wgpg, S2, B2, 3072);
  foldW_k<<<cdiv(256,4), 256, 0, stream>>>((const float*)d_in[I_PREDW], (const float*)d_in[I_LNG],
      (const float*)d_in[I_LNB], (const float*)d_in[I_PREDB], wpg, Sp, Bp, 256);
  vfold_k<<<cdiv(1024,4), 256, 0, stream>>>((const float*)d_in[I_DECW], 640, 0,
      (const float*)d_in[I_PREDB], (const float*)d_in[I_DECB], vX, 1024);
  vfold_k<<<cdiv(3072,4), 256, 0, stream>>>((const float*)d_in[I_WIH0], 1664, 1024,
      (const float*)d_in[I_PREDB], nullptr, vG, 3072);

  build_xc0_k<<<cdiv(32*640,256), 256, 0, stream>>>(pre_mo, aud_seq, lxm_b, xc0);
  gemm_bt<<<dim3(1,16), 256, 0, stream>>>(xc0, 640, wd_b, 640, (const float*)d_in[I_DECB],
      emb0, 32, 1024, 640, GELU_FLG|BF16_FLG);
  swz_emb_k<<<cdiv(32*1024,256), 256, 0, stream>>>(emb0, embR);
  gemm_bt<<<dim3(1,48), 256, 0, stream>>>(xc0, 640, wih0_b + 1024, 1664, nullptr,
      GxR, 32, 3072, 640, 0);

  hipMemsetAsync(syncb, 0, (size_t)512*16*4, stream);

  DecArgs da;
  da.aud_seq = aud_seq; da.lxm_b = lxm_b;
  da.wih0 = wih0_b; da.whh0 = whh0_b; da.wih1 = wih1_b; da.whh1 = whh1_b; da.wd = wd_b;
  da.wpg = wpg; da.Wdpg = Wdpg; da.Wgpg = Wgpg;
  da.Sp = Sp; da.Bp = Bp; da.S1 = S1; da.B1 = B1; da.S2 = S2; da.B2 = B2; da.vX = vX; da.vG = vG;
  da.bih0 = (const float*)d_in[I_BIH0]; da.bhh0 = (const float*)d_in[I_BHH0];
  da.bih1 = (const float*)d_in[I_BIH1]; da.bhh1 = (const float*)d_in[I_BHH1];
  da.h0init = h0i; da.h1init = h1i;
  da.embR = embR; da.h0R = h0R; da.h1R = h1R; da.statsR = statsR;
  da.GxR = GxR; da.XalR = XalR; da.GalR = GalR;
  da.h0f = h0f; da.h1f = h1f;
  da.out = out; da.sync = syncb;
  decode_k<<<dim3(NBLK), dim3(256), 0, stream>>>(da);
}